// Round 8
// baseline (525.613 us; speedup 1.0000x reference)
//
#include <hip/hip_runtime.h>
#include <cstdint>
#include <cstddef>

#define NTOK   16
#define MSTEPS 12
#define HID    128
#define INSZ   32
#define SPB    32     // sequences per block
#define TPB    128    // threads per block (2 waves)

struct KeyArr { uint32_t k0[MSTEPS]; uint32_t k1[MSTEPS]; };

__host__ __device__ static inline uint32_t rotl32(uint32_t x, uint32_t d) {
  return (x << d) | (x >> (32u - d));
}

// Exact replica of JAX's threefry2x32 block cipher.
__host__ __device__ static inline void tf2x32(uint32_t k0, uint32_t k1,
                                              uint32_t x0, uint32_t x1,
                                              uint32_t &o0, uint32_t &o1) {
  const uint32_t ks2 = k0 ^ k1 ^ 0x1BD11BDAu;
  x0 += k0; x1 += k1;
  x0 += x1; x1 = rotl32(x1, 13); x1 ^= x0;
  x0 += x1; x1 = rotl32(x1, 15); x1 ^= x0;
  x0 += x1; x1 = rotl32(x1, 26); x1 ^= x0;
  x0 += x1; x1 = rotl32(x1,  6); x1 ^= x0;
  x0 += k1; x1 += ks2 + 1u;
  x0 += x1; x1 = rotl32(x1, 17); x1 ^= x0;
  x0 += x1; x1 = rotl32(x1, 29); x1 ^= x0;
  x0 += x1; x1 = rotl32(x1, 16); x1 ^= x0;
  x0 += x1; x1 = rotl32(x1, 24); x1 ^= x0;
  x0 += ks2; x1 += k0 + 2u;
  x0 += x1; x1 = rotl32(x1, 13); x1 ^= x0;
  x0 += x1; x1 = rotl32(x1, 15); x1 ^= x0;
  x0 += x1; x1 = rotl32(x1, 26); x1 ^= x0;
  x0 += x1; x1 = rotl32(x1,  6); x1 ^= x0;
  x0 += k0; x1 += k1 + 3u;
  x0 += x1; x1 = rotl32(x1, 17); x1 ^= x0;
  x0 += x1; x1 = rotl32(x1, 29); x1 ^= x0;
  x0 += x1; x1 = rotl32(x1, 16); x1 ^= x0;
  x0 += x1; x1 = rotl32(x1, 24); x1 ^= x0;
  x0 += k1; x1 += ks2 + 4u;
  x0 += x1; x1 = rotl32(x1, 13); x1 ^= x0;
  x0 += x1; x1 = rotl32(x1, 15); x1 ^= x0;
  x0 += x1; x1 = rotl32(x1, 26); x1 ^= x0;
  x0 += x1; x1 = rotl32(x1,  6); x1 ^= x0;
  x0 += ks2; x1 += k0 + 5u;
  o0 = x0; o1 = x1;
}

// Fast transcendentals on the HW pipes (v_exp_f32 / v_log_f32 / v_rcp_f32).
__device__ __forceinline__ float fast_exp(float x) { return __expf(x); }
__device__ __forceinline__ float fast_log(float x) { return __logf(x); }
__device__ __forceinline__ float fast_tanh(float x) {
  float ax = fabsf(x);
  float e  = __expf(2.0f * ax);
  float r  = fmaf(-2.0f, __builtin_amdgcn_rcpf(e + 1.0f), 1.0f);
  return copysignf(r, x);
}

// h[k][s] in LDS, 16B-chunk swizzled: logical chunk (s>>2) of row k stored at
// physical chunk (s>>2)^((k>>3)&7). Reads (fixed k, 4 consecutive s) are
// broadcast/conflict-free; column writes hit the 8-word/bank floor only.
__global__ __launch_bounds__(TPB)
void eq_sampler(const float* __restrict__ x0in, const float* __restrict__ h0in,
                const float* __restrict__ Wx,   const float* __restrict__ Wh,
                const float* __restrict__ bvec, const float* __restrict__ Wp,
                const float* __restrict__ bp,   float* __restrict__ out,
                int n, KeyArr keys)
{
  __shared__ float hs[HID * SPB];     // 16 KB
  __shared__ float lgs[SPB * 17];     // staged raw logits (stride 17)
  __shared__ float h1s[HID];          // shared h_1 (identical across seqs)
  __shared__ float z1s[HID];          // shared h_1 @ Wh
  __shared__ float lgs0[NTOK];        // shared logits_0 (raw)
  __shared__ int   ps0_s[SPB], ps1_s[SPB];

  const int tid   = threadIdx.x;
  const int sg    = tid >> 4,  cg = tid & 15;     // sg 0..7, cg 0..15
  const int srow  = sg * 4,    cbase = cg * 8;
  const int gbase = blockIdx.x * SPB;
  const bool sampler = tid < 2 * SPB;             // first 64 threads
  const int seq   = tid >> 1,  th = tid & 1;      // valid when sampler
  const int gseq  = gbase + (sampler ? seq : 0);
  const float TINY = 1.17549435e-38f;

  // ---- prologue A: h_1 = tanh(x0@Wx + h0@Wh + b) — identical for all seqs --
  {
    float xw = 0.f;
    for (int k = 0; k < INSZ; ++k) xw = fmaf(x0in[k], Wx[k * HID + tid], xw);
    float a = 0.f;
    for (int k = 0; k < HID; ++k)  a = fmaf(h0in[k], Wh[k * HID + tid], a);
    h1s[tid] = fast_tanh((xw + a) + bvec[tid]);
  }
  __syncthreads();
  // ---- prologue B: z1 = h1@Wh (shared); logits0 = h1@Wp (threads 112..127) --
  {
    float a = 0.f;
    for (int k = 0; k < HID; ++k) a = fmaf(h1s[k], Wh[k * HID + tid], a);
    z1s[tid] = a;
  }
  if (tid >= TPB - NTOK) {
    const int j = tid - (TPB - NTOK);
    float a = 0.f;
    for (int k = 0; k < HID; ++k) a = fmaf(h1s[k], Wp[k * NTOK + j], a);
    lgs0[j] = a;
  }

  float bb[8], bpv[8];
  #pragma unroll
  for (int c = 0; c < 8; ++c) bb[c] = bvec[cbase + c];
  #pragma unroll
  for (int j = 0; j < 8; ++j) bpv[j] = bp[th * 8 + j];

  // per-seq state (replicated in both th threads of a pair)
  int cnt = 1, lengths = 1;
  bool act = true, hasvar = false;
  uint64_t pack = 0;

  float* o_seq = out;
  float* o_ent = out + (size_t)n * 12;
  float* o_lp  = out + (size_t)n * 24;
  float* o_cnt = out + (size_t)n * 36;
  float* o_len = out + (size_t)n * 37;
  float* o_msk = out + (size_t)n * 38;

  if (sampler && th == 0 && gseq < n) o_msk[(size_t)gseq * 13] = 1.0f;

  float acc[4][8];
  float accP[4];

  for (int t = 0; t < MSTEPS; ++t) {
    if (t > 0) {
      // ---- fused GEMM: h_cur @ [Wh | Wp-col(cg)] ----
      #pragma unroll
      for (int s = 0; s < 4; ++s) {
        accP[s] = 0.f;
        #pragma unroll
        for (int c = 0; c < 8; ++c) acc[s][c] = 0.f;
      }
      #pragma unroll 1
      for (int oct = 0; oct < 16; ++oct) {
        const int kb   = oct * 8;
        const int hw   = kb * SPB + (((sg ^ oct) & 7) << 2);   // word offset
        const float* wo = Wh + (size_t)kb * HID + cbase;
        const float* po = Wp + kb * NTOK + cg;
        #pragma unroll
        for (int kk = 0; kk < 8; ++kk) {
          float4 h4 = *(const float4*)&hs[hw + kk * SPB];
          float4 w0 = *(const float4*)(wo + kk * HID);
          float4 w1 = *(const float4*)(wo + kk * HID + 4);
          float  pw = po[kk * NTOK];
          #pragma unroll
          for (int s = 0; s < 4; ++s) {
            const float hv = s == 0 ? h4.x : s == 1 ? h4.y : s == 2 ? h4.z : h4.w;
            acc[s][0] = fmaf(hv, w0.x, acc[s][0]);
            acc[s][1] = fmaf(hv, w0.y, acc[s][1]);
            acc[s][2] = fmaf(hv, w0.z, acc[s][2]);
            acc[s][3] = fmaf(hv, w0.w, acc[s][3]);
            acc[s][4] = fmaf(hv, w1.x, acc[s][4]);
            acc[s][5] = fmaf(hv, w1.y, acc[s][5]);
            acc[s][6] = fmaf(hv, w1.z, acc[s][6]);
            acc[s][7] = fmaf(hv, w1.w, acc[s][7]);
            accP[s]   = fmaf(hv, pw,   accP[s]);
          }
        }
      }
      // stage raw logits
      #pragma unroll
      for (int s = 0; s < 4; ++s) lgs[(srow + s) * 17 + cg] = accP[s];
    }
    __syncthreads();

    // ---- sampling: 2 threads per seq, 8 tokens each (round-7 bit-orders) ----
    if (sampler) {
      float lg[8];
      if (t == 0) {
        #pragma unroll
        for (int j = 0; j < 8; ++j) lg[j] = lgs0[th * 8 + j];
      } else {
        #pragma unroll
        for (int j = 0; j < 8; ++j) lg[j] = lgs[seq * 17 + th * 8 + j];
      }
      #pragma unroll
      for (int j = 0; j < 8; ++j) lg[j] += bpv[j];

      float m8 = lg[0];
      #pragma unroll
      for (int j = 1; j < 8; ++j) m8 = fmaxf(m8, lg[j]);
      float mm = fmaxf(m8, __shfl_xor(m8, 1));

      float e[8]; float Zp = 0.f;
      #pragma unroll
      for (int j = 0; j < 8; ++j) { e[j] = fast_exp(lg[j] - mm); Zp += e[j]; }
      float Z = Zp + __shfl_xor(Zp, 1);

      const int cntv = cnt;
      const int cl   = cntv + t;
      const int hasv = hasvar ? 1 : 0;

      float pr[8]; float Sp = 0.f;
      #pragma unroll
      for (int j = 0; j < 8; ++j) {
        const int tj = th * 8 + j;
        float p = e[j] / Z;
        if (tj >= 8 && cl < 2)                p = 0.f;
        if (tj <  8 && cl > MSTEPS - 2)       p = 0.f;
        if (tj == 8 && cntv == 1 && !hasv)    p = 0.f;
        pr[j] = p; Sp += p;
      }
      float S = Sp + __shfl_xor(Sp, 1);

      float bs = 0.f, blp = 0.f, ep = 0.f; int bj = 0;
      #pragma unroll
      for (int j = 0; j < 8; ++j) {
        const int tj = th * 8 + j;
        float p = pr[j] / S;
        bool pos = p > 0.f;
        float lgpj = pos ? fast_log(p) : -__builtin_inff();
        ep += pos ? p * lgpj : 0.f;
        uint32_t b1, b2;
        tf2x32(keys.k0[t], keys.k1[t], 0u,
               (uint32_t)gseq * 16u + (uint32_t)tj, b1, b2);
        uint32_t bits = b1 ^ b2;
        float uf = __uint_as_float((bits >> 9) | 0x3F800000u) - 1.0f;
        uf += TINY; uf = fmaxf(TINY, uf);
        float g = -fast_log(-fast_log(uf));
        float sc = lgpj + g;
        if (j == 0) { bs = sc; bj = tj; blp = lgpj; }
        else if (sc > bs) { bs = sc; bj = tj; blp = lgpj; }
      }
      {
        float obs  = __shfl_xor(bs, 1);
        int   obj  = __shfl_xor(bj, 1);
        float oblp = __shfl_xor(blp, 1);
        if (obs > bs || (obs == bs && obj < bj)) { bs = obs; bj = obj; blp = oblp; }
      }
      float ent = -(ep + __shfl_xor(ep, 1));
      const int tok = bj;

      // state update (both th threads, identically)
      cnt += -1 + (tok < 4 ? 2 : (tok < 8 ? 1 : 0));
      act = act && (cnt > 0);
      lengths += act ? 1 : 0;
      if (tok >= 9) hasvar = true;
      pack |= (uint64_t)(uint32_t)tok << (4 * t);

      if (th == 0) {
        if (gseq < n) {
          o_ent[(size_t)gseq * 12 + t] = ent;
          o_lp [(size_t)gseq * 12 + t] = blp;
          o_msk[(size_t)gseq * 13 + t + 1] = act ? 1.f : 0.f;
        }
        // parent & sibling from packed tokens
        int np0, np1;
        if (tok < 8) { np0 = tok; np1 = -1; }
        else {
          int c = 0, p0 = -1, p1 = -1;
          for (int i = t; i >= 0; --i) {
            int tk = (int)((pack >> (4 * i)) & 15u);
            c += (tk < 4 ? 2 : (tk < 8 ? 1 : 0)) - 1;
            if (c == 0 && p0 < 0) {
              p0 = tk;
              p1 = (i < t) ? (int)((pack >> (4 * (i + 1))) & 15u) : -1;
            }
          }
          np0 = p0; np1 = p1;
        }
        ps0_s[seq] = np0; ps1_s[seq] = np1;
      }
    }
    __syncthreads();

    if (t < MSTEPS - 1) {
      // ---- epilogue: h_next = tanh((xw + z) + b), write to hs ----
      #pragma unroll
      for (int s = 0; s < 4; ++s) {
        const int sq = srow + s;
        const int p0 = ps0_s[sq], p1 = ps1_s[sq];
        float av[8], cv[8];
        #pragma unroll
        for (int c = 0; c < 8; ++c) { av[c] = 0.f; cv[c] = 0.f; }
        if (p0 >= 0) {
          float4 u0 = *(const float4*)&Wx[p0 * HID + cbase];
          float4 u1 = *(const float4*)&Wx[p0 * HID + cbase + 4];
          av[0]=u0.x; av[1]=u0.y; av[2]=u0.z; av[3]=u0.w;
          av[4]=u1.x; av[5]=u1.y; av[6]=u1.z; av[7]=u1.w;
        }
        if (p1 >= 0) {
          float4 u0 = *(const float4*)&Wx[(NTOK + p1) * HID + cbase];
          float4 u1 = *(const float4*)&Wx[(NTOK + p1) * HID + cbase + 4];
          cv[0]=u0.x; cv[1]=u0.y; cv[2]=u0.z; cv[3]=u0.w;
          cv[4]=u1.x; cv[5]=u1.y; cv[6]=u1.z; cv[7]=u1.w;
        }
        #pragma unroll
        for (int c = 0; c < 8; ++c) {
          float zz = t == 0 ? z1s[cbase + c] : acc[s][c];
          acc[s][c] = fast_tanh(((av[c] + cv[c]) + zz) + bb[c]);
        }
      }
      #pragma unroll
      for (int c = 0; c < 8; ++c) {
        const int col = cbase + c;
        const int wb  = col * SPB + (((sg ^ (col >> 3)) & 7) << 2);
        *(float4*)&hs[wb] =
            make_float4(acc[0][c], acc[1][c], acc[2][c], acc[3][c]);
      }
    }
    __syncthreads();
  }

  if (sampler && th == 0 && gseq < n) {
    o_cnt[gseq] = (float)cnt;
    o_len[gseq] = (float)lengths;
    #pragma unroll
    for (int j = 0; j < MSTEPS; ++j)
      o_seq[(size_t)gseq * 12 + j] = (float)((pack >> (4 * j)) & 15u);
  }
}

extern "C" void kernel_launch(void* const* d_in, const int* in_sizes, int n_in,
                              void* d_out, int out_size, void* d_ws, size_t ws_size,
                              hipStream_t stream) {
  const float* x0 = (const float*)d_in[1];
  const float* h0 = (const float*)d_in[2];
  const float* Wx = (const float*)d_in[3];
  const float* Wh = (const float*)d_in[4];
  const float* bv = (const float*)d_in[5];
  const float* Wp = (const float*)d_in[6];
  const float* bp = (const float*)d_in[7];
  float* out = (float*)d_out;

  int n = out_size / 51;   // 12+12+12+1+1+13 floats per sequence

  // jax.random.split(jax.random.key(42), 12), partitionable threefry:
  // keys[t] = threefry((0,42), (0, t)).
  KeyArr ka;
  for (int t = 0; t < 12; ++t) {
    uint32_t o0, o1;
    tf2x32(0u, 42u, 0u, (uint32_t)t, o0, o1);
    ka.k0[t] = o0; ka.k1[t] = o1;
  }

  int blocks = (n + SPB - 1) / SPB;
  eq_sampler<<<blocks, TPB, 0, stream>>>(x0, h0, Wx, Wh, bv, Wp, bp, out, n, ka);
}

// Round 9
// 500.253 us; speedup vs baseline: 1.0507x; 1.0507x over previous
//
#include <hip/hip_runtime.h>
#include <cstdint>
#include <cstddef>

#define NTOK   16
#define MSTEPS 12
#define HID    128
#define INSZ   32
#define SPB    64     // sequences per block
#define TPB    256    // threads per block (4 waves)

typedef float f32x2 __attribute__((ext_vector_type(2)));

struct KeyArr { uint32_t k0[MSTEPS]; uint32_t k1[MSTEPS]; };

__host__ __device__ static inline uint32_t rotl32(uint32_t x, uint32_t d) {
  return (x << d) | (x >> (32u - d));
}

// Exact replica of JAX's threefry2x32 block cipher.
__host__ __device__ static inline void tf2x32(uint32_t k0, uint32_t k1,
                                              uint32_t x0, uint32_t x1,
                                              uint32_t &o0, uint32_t &o1) {
  const uint32_t ks2 = k0 ^ k1 ^ 0x1BD11BDAu;
  x0 += k0; x1 += k1;
  x0 += x1; x1 = rotl32(x1, 13); x1 ^= x0;
  x0 += x1; x1 = rotl32(x1, 15); x1 ^= x0;
  x0 += x1; x1 = rotl32(x1, 26); x1 ^= x0;
  x0 += x1; x1 = rotl32(x1,  6); x1 ^= x0;
  x0 += k1; x1 += ks2 + 1u;
  x0 += x1; x1 = rotl32(x1, 17); x1 ^= x0;
  x0 += x1; x1 = rotl32(x1, 29); x1 ^= x0;
  x0 += x1; x1 = rotl32(x1, 16); x1 ^= x0;
  x0 += x1; x1 = rotl32(x1, 24); x1 ^= x0;
  x0 += ks2; x1 += k0 + 2u;
  x0 += x1; x1 = rotl32(x1, 13); x1 ^= x0;
  x0 += x1; x1 = rotl32(x1, 15); x1 ^= x0;
  x0 += x1; x1 = rotl32(x1, 26); x1 ^= x0;
  x0 += x1; x1 = rotl32(x1,  6); x1 ^= x0;
  x0 += k0; x1 += k1 + 3u;
  x0 += x1; x1 = rotl32(x1, 17); x1 ^= x0;
  x0 += x1; x1 = rotl32(x1, 29); x1 ^= x0;
  x0 += x1; x1 = rotl32(x1, 16); x1 ^= x0;
  x0 += x1; x1 = rotl32(x1, 24); x1 ^= x0;
  x0 += k1; x1 += ks2 + 4u;
  x0 += x1; x1 = rotl32(x1, 13); x1 ^= x0;
  x0 += x1; x1 = rotl32(x1, 15); x1 ^= x0;
  x0 += x1; x1 = rotl32(x1, 26); x1 ^= x0;
  x0 += x1; x1 = rotl32(x1,  6); x1 ^= x0;
  x0 += ks2; x1 += k0 + 5u;
  o0 = x0; o1 = x1;
}

// Fast transcendentals on the HW pipes (v_exp_f32 / v_log_f32 / v_rcp_f32).
__device__ __forceinline__ float fast_exp(float x) { return __expf(x); }
__device__ __forceinline__ float fast_log(float x) { return __logf(x); }
__device__ __forceinline__ float fast_tanh(float x) {
  float ax = fabsf(x);
  float e  = __expf(2.0f * ax);
  float r  = fmaf(-2.0f, __builtin_amdgcn_rcpf(e + 1.0f), 1.0f);
  return copysignf(r, x);
}

// Packed f32x2 FMA — selects v_pk_fma_f32; per-element semantics == fmaf,
// so accumulator bit-patterns are identical to the scalar formulation.
__device__ __forceinline__ f32x2 pkfma(f32x2 a, f32x2 b, f32x2 c) {
  return __builtin_elementwise_fma(a, b, c);
}

// h[k][s] in LDS, 16B-chunk swizzled: logical chunk (s>>2) stored at physical
// chunk (s>>2)^((k>>3)&15). Reads (fixed k, 4 consecutive s) and writes
// (fixed col k, 4 consecutive s) are both b128 and >=2-way-conflict-free.
__global__ __launch_bounds__(TPB)
void eq_sampler(const float* __restrict__ x0in, const float* __restrict__ h0in,
                const float* __restrict__ Wx,   const float* __restrict__ Wh,
                const float* __restrict__ bvec, const float* __restrict__ Wp,
                const float* __restrict__ bp,   float* __restrict__ out,
                int n, KeyArr keys)
{
  __shared__ float hs[HID * SPB];     // 32 KB
  __shared__ float lgs[SPB * 17];     // staged raw logits (stride 17)
  __shared__ float h1s[HID];          // shared h_1 (identical across seqs)
  __shared__ float z1s[HID];          // shared h_1 @ Wh
  __shared__ float lgs0[NTOK];        // shared logits_0 (raw)
  __shared__ int   ps0_s[SPB], ps1_s[SPB];

  const int tid   = threadIdx.x;
  const int sg    = tid >> 4,  cg = tid & 15;
  const int srow  = sg * 4,    cbase = cg * 8;
  const int gbase = blockIdx.x * SPB;
  const bool sampler = tid < 2 * SPB;
  const int seq   = tid >> 1,  th = tid & 1;      // valid when sampler
  const int gseq  = gbase + (sampler ? seq : 0);
  const float TINY = 1.17549435e-38f;

  // ---- prologue A: h_1 = tanh(x0@Wx + h0@Wh + b) — identical for all seqs --
  if (tid < HID) {
    float xw = 0.f;
    for (int k = 0; k < INSZ; ++k) xw = fmaf(x0in[k], Wx[k * HID + tid], xw);
    float a = 0.f;
    for (int k = 0; k < HID; ++k)  a = fmaf(h0in[k], Wh[k * HID + tid], a);
    h1s[tid] = fast_tanh((xw + a) + bvec[tid]);
  }
  __syncthreads();
  // ---- prologue B: z1 = h1@Wh (shared), logits0 = h1@Wp (shared) ----
  if (tid < HID) {
    float a = 0.f;
    for (int k = 0; k < HID; ++k) a = fmaf(h1s[k], Wh[k * HID + tid], a);
    z1s[tid] = a;
  } else if (tid < HID + NTOK) {
    const int j = tid - HID;
    float a = 0.f;
    for (int k = 0; k < HID; ++k) a = fmaf(h1s[k], Wp[k * NTOK + j], a);
    lgs0[j] = a;
  }

  float bb[8], bpv[8];
  #pragma unroll
  for (int c = 0; c < 8; ++c) bb[c] = bvec[cbase + c];
  #pragma unroll
  for (int j = 0; j < 8; ++j) bpv[j] = bp[th * 8 + j];

  // per-seq state (replicated in both th threads of a pair)
  int cnt = 1, lengths = 1;
  bool act = true, hasvar = false;
  uint64_t pack = 0;

  float* o_seq = out;
  float* o_ent = out + (size_t)n * 12;
  float* o_lp  = out + (size_t)n * 24;
  float* o_cnt = out + (size_t)n * 36;
  float* o_len = out + (size_t)n * 37;
  float* o_msk = out + (size_t)n * 38;

  if (sampler && th == 0 && gseq < n) o_msk[(size_t)gseq * 13] = 1.0f;

  f32x2 acc2[4][4];   // [seq][col-pair]
  f32x2 accP2[2];     // logits col: seq-pairs (0,1) and (2,3)

  for (int t = 0; t < MSTEPS; ++t) {
    if (t > 0) {
      // ---- fused GEMM: h_cur @ [Wh | Wp-col(cg)], packed f32x2 FMA ----
      #pragma unroll
      for (int s = 0; s < 4; ++s) {
        #pragma unroll
        for (int c = 0; c < 4; ++c) acc2[s][c] = (f32x2){0.f, 0.f};
      }
      accP2[0] = (f32x2){0.f, 0.f};
      accP2[1] = (f32x2){0.f, 0.f};
      #pragma unroll 1
      for (int oct = 0; oct < 16; ++oct) {
        const int kb   = oct * 8;
        const int hw   = kb * SPB + ((sg ^ oct) << 2);   // word offset
        const float* wo = Wh + (size_t)kb * HID + cbase;
        const float* po = Wp + kb * NTOK + cg;
        #pragma unroll
        for (int kk = 0; kk < 8; ++kk) {
          float4 h4 = *(const float4*)&hs[hw + kk * SPB];
          float4 w0 = *(const float4*)(wo + kk * HID);
          float4 w1 = *(const float4*)(wo + kk * HID + 4);
          float  pw = po[kk * NTOK];
          const f32x2 wA = {w0.x, w0.y}, wB = {w0.z, w0.w};
          const f32x2 wC = {w1.x, w1.y}, wD = {w1.z, w1.w};
          const f32x2 pw2 = {pw, pw};
          #pragma unroll
          for (int s = 0; s < 4; ++s) {
            const float hv = s == 0 ? h4.x : s == 1 ? h4.y : s == 2 ? h4.z : h4.w;
            const f32x2 hv2 = {hv, hv};
            acc2[s][0] = pkfma(hv2, wA, acc2[s][0]);
            acc2[s][1] = pkfma(hv2, wB, acc2[s][1]);
            acc2[s][2] = pkfma(hv2, wC, acc2[s][2]);
            acc2[s][3] = pkfma(hv2, wD, acc2[s][3]);
          }
          accP2[0] = pkfma((f32x2){h4.x, h4.y}, pw2, accP2[0]);
          accP2[1] = pkfma((f32x2){h4.z, h4.w}, pw2, accP2[1]);
        }
      }
      // stage raw logits (same values/order as scalar accP[s])
      lgs[(srow + 0) * 17 + cg] = accP2[0].x;
      lgs[(srow + 1) * 17 + cg] = accP2[0].y;
      lgs[(srow + 2) * 17 + cg] = accP2[1].x;
      lgs[(srow + 3) * 17 + cg] = accP2[1].y;
    }
    __syncthreads();

    // ---- sampling: 2 threads per seq, 8 tokens each (round-7 bit-orders) ----
    if (sampler) {
      float lg[8];
      if (t == 0) {
        #pragma unroll
        for (int j = 0; j < 8; ++j) lg[j] = lgs0[th * 8 + j];
      } else {
        #pragma unroll
        for (int j = 0; j < 8; ++j) lg[j] = lgs[seq * 17 + th * 8 + j];
      }
      #pragma unroll
      for (int j = 0; j < 8; ++j) lg[j] += bpv[j];

      float m8 = lg[0];
      #pragma unroll
      for (int j = 1; j < 8; ++j) m8 = fmaxf(m8, lg[j]);
      float mm = fmaxf(m8, __shfl_xor(m8, 1));

      float e[8]; float Zp = 0.f;
      #pragma unroll
      for (int j = 0; j < 8; ++j) { e[j] = fast_exp(lg[j] - mm); Zp += e[j]; }
      float Z = Zp + __shfl_xor(Zp, 1);

      const int cntv = cnt;
      const int cl   = cntv + t;
      const int hasv = hasvar ? 1 : 0;

      float pr[8]; float Sp = 0.f;
      #pragma unroll
      for (int j = 0; j < 8; ++j) {
        const int tj = th * 8 + j;
        float p = e[j] / Z;
        if (tj >= 8 && cl < 2)                p = 0.f;
        if (tj <  8 && cl > MSTEPS - 2)       p = 0.f;
        if (tj == 8 && cntv == 1 && !hasv)    p = 0.f;
        pr[j] = p; Sp += p;
      }
      float S = Sp + __shfl_xor(Sp, 1);

      float bs = 0.f, blp = 0.f, ep = 0.f; int bj = 0;
      #pragma unroll
      for (int j = 0; j < 8; ++j) {
        const int tj = th * 8 + j;
        float p = pr[j] / S;
        bool pos = p > 0.f;
        float lgpj = pos ? fast_log(p) : -__builtin_inff();
        ep += pos ? p * lgpj : 0.f;
        uint32_t b1, b2;
        tf2x32(keys.k0[t], keys.k1[t], 0u,
               (uint32_t)gseq * 16u + (uint32_t)tj, b1, b2);
        uint32_t bits = b1 ^ b2;
        float uf = __uint_as_float((bits >> 9) | 0x3F800000u) - 1.0f;
        uf += TINY; uf = fmaxf(TINY, uf);
        float g = -fast_log(-fast_log(uf));
        float sc = lgpj + g;
        if (j == 0) { bs = sc; bj = tj; blp = lgpj; }
        else if (sc > bs) { bs = sc; bj = tj; blp = lgpj; }
      }
      {
        float obs  = __shfl_xor(bs, 1);
        int   obj  = __shfl_xor(bj, 1);
        float oblp = __shfl_xor(blp, 1);
        if (obs > bs || (obs == bs && obj < bj)) { bs = obs; bj = obj; blp = oblp; }
      }
      float ent = -(ep + __shfl_xor(ep, 1));
      const int tok = bj;

      // state update (both th threads, identically)
      cnt += -1 + (tok < 4 ? 2 : (tok < 8 ? 1 : 0));
      act = act && (cnt > 0);
      lengths += act ? 1 : 0;
      if (tok >= 9) hasvar = true;
      pack |= (uint64_t)(uint32_t)tok << (4 * t);

      if (th == 0) {
        if (gseq < n) {
          o_ent[(size_t)gseq * 12 + t] = ent;
          o_lp [(size_t)gseq * 12 + t] = blp;
          o_msk[(size_t)gseq * 13 + t + 1] = act ? 1.f : 0.f;
        }
        // parent & sibling from packed tokens
        int np0, np1;
        if (tok < 8) { np0 = tok; np1 = -1; }
        else {
          int c = 0, p0 = -1, p1 = -1;
          for (int i = t; i >= 0; --i) {
            int tk = (int)((pack >> (4 * i)) & 15u);
            c += (tk < 4 ? 2 : (tk < 8 ? 1 : 0)) - 1;
            if (c == 0 && p0 < 0) {
              p0 = tk;
              p1 = (i < t) ? (int)((pack >> (4 * (i + 1))) & 15u) : -1;
            }
          }
          np0 = p0; np1 = p1;
        }
        ps0_s[seq] = np0; ps1_s[seq] = np1;
      }
    }
    __syncthreads();

    if (t < MSTEPS - 1) {
      // ---- epilogue: h_next = tanh((xw + z) + b), write to hs ----
      float hnew[4][8];
      #pragma unroll
      for (int s = 0; s < 4; ++s) {
        const int sq = srow + s;
        const int p0 = ps0_s[sq], p1 = ps1_s[sq];
        float av[8], cv[8];
        #pragma unroll
        for (int c = 0; c < 8; ++c) { av[c] = 0.f; cv[c] = 0.f; }
        if (p0 >= 0) {
          float4 u0 = *(const float4*)&Wx[p0 * HID + cbase];
          float4 u1 = *(const float4*)&Wx[p0 * HID + cbase + 4];
          av[0]=u0.x; av[1]=u0.y; av[2]=u0.z; av[3]=u0.w;
          av[4]=u1.x; av[5]=u1.y; av[6]=u1.z; av[7]=u1.w;
        }
        if (p1 >= 0) {
          float4 u0 = *(const float4*)&Wx[(NTOK + p1) * HID + cbase];
          float4 u1 = *(const float4*)&Wx[(NTOK + p1) * HID + cbase + 4];
          cv[0]=u0.x; cv[1]=u0.y; cv[2]=u0.z; cv[3]=u0.w;
          cv[4]=u1.x; cv[5]=u1.y; cv[6]=u1.z; cv[7]=u1.w;
        }
        #pragma unroll
        for (int c = 0; c < 8; ++c) {
          float zz = t == 0 ? z1s[cbase + c]
                            : ((c & 1) ? acc2[s][c >> 1].y : acc2[s][c >> 1].x);
          hnew[s][c] = fast_tanh(((av[c] + cv[c]) + zz) + bb[c]);
        }
      }
      const int wbase = ((sg ^ cg) << 2);
      #pragma unroll
      for (int c = 0; c < 8; ++c) {
        *(float4*)&hs[(cbase + c) * SPB + wbase] =
            make_float4(hnew[0][c], hnew[1][c], hnew[2][c], hnew[3][c]);
      }
    }
    __syncthreads();
  }

  if (sampler && th == 0 && gseq < n) {
    o_cnt[gseq] = (float)cnt;
    o_len[gseq] = (float)lengths;
    #pragma unroll
    for (int j = 0; j < MSTEPS; ++j)
      o_seq[(size_t)gseq * 12 + j] = (float)((pack >> (4 * j)) & 15u);
  }
}

extern "C" void kernel_launch(void* const* d_in, const int* in_sizes, int n_in,
                              void* d_out, int out_size, void* d_ws, size_t ws_size,
                              hipStream_t stream) {
  const float* x0 = (const float*)d_in[1];
  const float* h0 = (const float*)d_in[2];
  const float* Wx = (const float*)d_in[3];
  const float* Wh = (const float*)d_in[4];
  const float* bv = (const float*)d_in[5];
  const float* Wp = (const float*)d_in[6];
  const float* bp = (const float*)d_in[7];
  float* out = (float*)d_out;

  int n = out_size / 51;   // 12+12+12+1+1+13 floats per sequence

  // jax.random.split(jax.random.key(42), 12), partitionable threefry:
  // keys[t] = threefry((0,42), (0, t)).
  KeyArr ka;
  for (int t = 0; t < 12; ++t) {
    uint32_t o0, o1;
    tf2x32(0u, 42u, 0u, (uint32_t)t, o0, o1);
    ka.k0[t] = o0; ka.k1[t] = o1;
  }

  int blocks = (n + SPB - 1) / SPB;
  eq_sampler<<<blocks, TPB, 0, stream>>>(x0, h0, Wx, Wh, bv, Wp, bp, out, n, ka);
}

// Round 10
// 482.938 us; speedup vs baseline: 1.0884x; 1.0359x over previous
//
#include <hip/hip_runtime.h>
#include <cstdint>
#include <cstddef>

#define NTOK   16
#define MSTEPS 12
#define HID    128
#define INSZ   32
#define SPB    64     // sequences per block
#define TPB    256    // threads per block (4 waves)

typedef float f32x2 __attribute__((ext_vector_type(2)));

struct KeyArr { uint32_t k0[MSTEPS]; uint32_t k1[MSTEPS]; };

__host__ __device__ static inline uint32_t rotl32(uint32_t x, uint32_t d) {
  return (x << d) | (x >> (32u - d));
}

// Exact replica of JAX's threefry2x32 block cipher.
__host__ __device__ static inline void tf2x32(uint32_t k0, uint32_t k1,
                                              uint32_t x0, uint32_t x1,
                                              uint32_t &o0, uint32_t &o1) {
  const uint32_t ks2 = k0 ^ k1 ^ 0x1BD11BDAu;
  x0 += k0; x1 += k1;
  x0 += x1; x1 = rotl32(x1, 13); x1 ^= x0;
  x0 += x1; x1 = rotl32(x1, 15); x1 ^= x0;
  x0 += x1; x1 = rotl32(x1, 26); x1 ^= x0;
  x0 += x1; x1 = rotl32(x1,  6); x1 ^= x0;
  x0 += k1; x1 += ks2 + 1u;
  x0 += x1; x1 = rotl32(x1, 17); x1 ^= x0;
  x0 += x1; x1 = rotl32(x1, 29); x1 ^= x0;
  x0 += x1; x1 = rotl32(x1, 16); x1 ^= x0;
  x0 += x1; x1 = rotl32(x1, 24); x1 ^= x0;
  x0 += ks2; x1 += k0 + 2u;
  x0 += x1; x1 = rotl32(x1, 13); x1 ^= x0;
  x0 += x1; x1 = rotl32(x1, 15); x1 ^= x0;
  x0 += x1; x1 = rotl32(x1, 26); x1 ^= x0;
  x0 += x1; x1 = rotl32(x1,  6); x1 ^= x0;
  x0 += k0; x1 += k1 + 3u;
  x0 += x1; x1 = rotl32(x1, 17); x1 ^= x0;
  x0 += x1; x1 = rotl32(x1, 29); x1 ^= x0;
  x0 += x1; x1 = rotl32(x1, 16); x1 ^= x0;
  x0 += x1; x1 = rotl32(x1, 24); x1 ^= x0;
  x0 += k1; x1 += ks2 + 4u;
  x0 += x1; x1 = rotl32(x1, 13); x1 ^= x0;
  x0 += x1; x1 = rotl32(x1, 15); x1 ^= x0;
  x0 += x1; x1 = rotl32(x1, 26); x1 ^= x0;
  x0 += x1; x1 = rotl32(x1,  6); x1 ^= x0;
  x0 += ks2; x1 += k0 + 5u;
  o0 = x0; o1 = x1;
}

// Fast transcendentals on the HW pipes (v_exp_f32 / v_log_f32 / v_rcp_f32).
__device__ __forceinline__ float fast_exp(float x) { return __expf(x); }
__device__ __forceinline__ float fast_log(float x) { return __logf(x); }
__device__ __forceinline__ float fast_tanh(float x) {
  float ax = fabsf(x);
  float e  = __expf(2.0f * ax);
  float r  = fmaf(-2.0f, __builtin_amdgcn_rcpf(e + 1.0f), 1.0f);
  return copysignf(r, x);
}

// Packed f32x2 FMA — per-element semantics == fmaf (bit-identical chains).
__device__ __forceinline__ f32x2 pkfma(f32x2 a, f32x2 b, f32x2 c) {
  return __builtin_elementwise_fma(a, b, c);
}

__global__ __launch_bounds__(TPB)
void eq_sampler(const float* __restrict__ x0in, const float* __restrict__ h0in,
                const float* __restrict__ Wx,   const float* __restrict__ Wh,
                const float* __restrict__ bvec, const float* __restrict__ Wp,
                const float* __restrict__ bp,   float* __restrict__ out,
                int n, KeyArr keys)
{
  __shared__ float hs[HID * SPB];     // 32 KB
  __shared__ float lgs[SPB * 17];     // staged raw logits (stride 17)
  __shared__ float h1s[HID];          // shared h_1 (identical across seqs)
  __shared__ float z1s[HID];          // shared h_1 @ Wh
  __shared__ float lgs0[NTOK];        // shared logits_0 (raw)
  __shared__ int   ps0_s[SPB], ps1_s[SPB];

  const int tid   = threadIdx.x;
  // REMAP vs round 9: sg fast, cg slow — wave's 64 lanes now share only 4
  // distinct W-column groups (4x fewer L1/L2 lines for Wh), h-reads 16
  // distinct chunks (2-way conflict-free). All swizzle formulas unchanged.
  const int sg    = tid & 15,  cg = tid >> 4;
  const int srow  = sg * 4,    cbase = cg * 8;
  const int gbase = blockIdx.x * SPB;
  const int seq   = tid >> 2,  q = tid & 3;       // 4 sampler threads per seq
  const int gseq  = gbase + seq;
  const float TINY = 1.17549435e-38f;

  // ---- prologue A: h_1 = tanh(x0@Wx + h0@Wh + b) — identical for all seqs --
  if (tid < HID) {
    float xw = 0.f;
    for (int k = 0; k < INSZ; ++k) xw = fmaf(x0in[k], Wx[k * HID + tid], xw);
    float a = 0.f;
    for (int k = 0; k < HID; ++k)  a = fmaf(h0in[k], Wh[k * HID + tid], a);
    h1s[tid] = fast_tanh((xw + a) + bvec[tid]);
  }
  __syncthreads();
  // ---- prologue B: z1 = h1@Wh (shared), logits0 = h1@Wp (shared) ----
  if (tid < HID) {
    float a = 0.f;
    for (int k = 0; k < HID; ++k) a = fmaf(h1s[k], Wh[k * HID + tid], a);
    z1s[tid] = a;
  } else if (tid < HID + NTOK) {
    const int j = tid - HID;
    float a = 0.f;
    for (int k = 0; k < HID; ++k) a = fmaf(h1s[k], Wp[k * NTOK + j], a);
    lgs0[j] = a;
  }

  float bb[8], bpv[4];
  #pragma unroll
  for (int c = 0; c < 8; ++c) bb[c] = bvec[cbase + c];
  #pragma unroll
  for (int j = 0; j < 4; ++j) bpv[j] = bp[q * 4 + j];

  // per-seq state (replicated in all 4 threads of a quad)
  int cnt = 1, lengths = 1;
  bool act = true, hasvar = false;
  uint64_t pack = 0;

  float* o_seq = out;
  float* o_ent = out + (size_t)n * 12;
  float* o_lp  = out + (size_t)n * 24;
  float* o_cnt = out + (size_t)n * 36;
  float* o_len = out + (size_t)n * 37;
  float* o_msk = out + (size_t)n * 38;

  if (q == 0 && gseq < n) o_msk[(size_t)gseq * 13] = 1.0f;

  f32x2 acc2[4][4];   // [seq][col-pair]
  f32x2 accP2[2];     // logits col: seq-pairs (0,1) and (2,3)

  for (int t = 0; t < MSTEPS; ++t) {
    if (t > 0) {
      // ---- fused GEMM: h_cur @ [Wh | Wp-col(cg)], packed f32x2 FMA ----
      #pragma unroll
      for (int s = 0; s < 4; ++s) {
        #pragma unroll
        for (int c = 0; c < 4; ++c) acc2[s][c] = (f32x2){0.f, 0.f};
      }
      accP2[0] = (f32x2){0.f, 0.f};
      accP2[1] = (f32x2){0.f, 0.f};
      #pragma unroll 1
      for (int oct = 0; oct < 16; ++oct) {
        const int kb   = oct * 8;
        const int hw   = kb * SPB + ((sg ^ oct) << 2);   // word offset
        const float* wo = Wh + (size_t)kb * HID + cbase;
        const float* po = Wp + kb * NTOK + cg;
        #pragma unroll
        for (int kk = 0; kk < 8; ++kk) {
          float4 h4 = *(const float4*)&hs[hw + kk * SPB];
          float4 w0 = *(const float4*)(wo + kk * HID);
          float4 w1 = *(const float4*)(wo + kk * HID + 4);
          float  pw = po[kk * NTOK];
          const f32x2 wA = {w0.x, w0.y}, wB = {w0.z, w0.w};
          const f32x2 wC = {w1.x, w1.y}, wD = {w1.z, w1.w};
          const f32x2 pw2 = {pw, pw};
          #pragma unroll
          for (int s = 0; s < 4; ++s) {
            const float hv = s == 0 ? h4.x : s == 1 ? h4.y : s == 2 ? h4.z : h4.w;
            const f32x2 hv2 = {hv, hv};
            acc2[s][0] = pkfma(hv2, wA, acc2[s][0]);
            acc2[s][1] = pkfma(hv2, wB, acc2[s][1]);
            acc2[s][2] = pkfma(hv2, wC, acc2[s][2]);
            acc2[s][3] = pkfma(hv2, wD, acc2[s][3]);
          }
          accP2[0] = pkfma((f32x2){h4.x, h4.y}, pw2, accP2[0]);
          accP2[1] = pkfma((f32x2){h4.z, h4.w}, pw2, accP2[1]);
        }
      }
      // stage raw logits (same values/order as scalar accP[s])
      lgs[(srow + 0) * 17 + cg] = accP2[0].x;
      lgs[(srow + 1) * 17 + cg] = accP2[0].y;
      lgs[(srow + 2) * 17 + cg] = accP2[1].x;
      lgs[(srow + 3) * 17 + cg] = accP2[1].y;
    }
    __syncthreads();

    // ---- sampling: 4 threads per seq, 4 tokens each ----
    {
      float lg[4];
      if (t == 0) {
        #pragma unroll
        for (int j = 0; j < 4; ++j) lg[j] = lgs0[q * 4 + j];
      } else {
        #pragma unroll
        for (int j = 0; j < 4; ++j) lg[j] = lgs[seq * 17 + q * 4 + j];
      }
      #pragma unroll
      for (int j = 0; j < 4; ++j) lg[j] += bpv[j];

      // max over 16 (exact, order-free)
      float m4 = lg[0];
      #pragma unroll
      for (int j = 1; j < 4; ++j) m4 = fmaxf(m4, lg[j]);
      float mm = fmaxf(m4, __shfl_xor(m4, 1));
      mm = fmaxf(mm, __shfl_xor(mm, 2));

      float e[4]; float Zp = 0.f;
      #pragma unroll
      for (int j = 0; j < 4; ++j) { e[j] = fast_exp(lg[j] - mm); Zp += e[j]; }
      float Z = Zp + __shfl_xor(Zp, 1);
      Z += __shfl_xor(Z, 2);

      const int cntv = cnt;
      const int cl   = cntv + t;
      const int hasv = hasvar ? 1 : 0;

      float pr[4]; float Sp = 0.f;
      #pragma unroll
      for (int j = 0; j < 4; ++j) {
        const int tj = q * 4 + j;
        float p = e[j] / Z;
        if (tj >= 8 && cl < 2)                p = 0.f;
        if (tj <  8 && cl > MSTEPS - 2)       p = 0.f;
        if (tj == 8 && cntv == 1 && !hasv)    p = 0.f;
        pr[j] = p; Sp += p;
      }
      float S = Sp + __shfl_xor(Sp, 1);
      S += __shfl_xor(S, 2);

      float bs = 0.f, blp = 0.f, ep = 0.f; int bj = 0;
      #pragma unroll
      for (int j = 0; j < 4; ++j) {
        const int tj = q * 4 + j;
        float p = pr[j] / S;
        bool pos = p > 0.f;
        float lgpj = pos ? fast_log(p) : -__builtin_inff();
        ep += pos ? p * lgpj : 0.f;
        uint32_t b1, b2;
        tf2x32(keys.k0[t], keys.k1[t], 0u,
               (uint32_t)gseq * 16u + (uint32_t)tj, b1, b2);
        uint32_t bits = b1 ^ b2;
        float uf = __uint_as_float((bits >> 9) | 0x3F800000u) - 1.0f;
        uf += TINY; uf = fmaxf(TINY, uf);
        float g = -fast_log(-fast_log(uf));
        float sc = lgpj + g;
        if (j == 0) { bs = sc; bj = tj; blp = lgpj; }
        else if (sc > bs) { bs = sc; bj = tj; blp = lgpj; }
      }
      // argmax tree, lowest-index-on-tie preserved
      {
        float obs  = __shfl_xor(bs, 1);
        int   obj  = __shfl_xor(bj, 1);
        float oblp = __shfl_xor(blp, 1);
        if (obs > bs || (obs == bs && obj < bj)) { bs = obs; bj = obj; blp = oblp; }
      }
      {
        float obs  = __shfl_xor(bs, 2);
        int   obj  = __shfl_xor(bj, 2);
        float oblp = __shfl_xor(blp, 2);
        if (obs > bs || (obs == bs && obj < bj)) { bs = obs; bj = obj; blp = oblp; }
      }
      float ept = ep + __shfl_xor(ep, 1);
      ept += __shfl_xor(ept, 2);
      float ent = -ept;
      const int tok = bj;

      // state update (all 4 quad threads, identically)
      cnt += -1 + (tok < 4 ? 2 : (tok < 8 ? 1 : 0));
      act = act && (cnt > 0);
      lengths += act ? 1 : 0;
      if (tok >= 9) hasvar = true;
      pack |= (uint64_t)(uint32_t)tok << (4 * t);

      if (q == 0) {
        if (gseq < n) {
          o_ent[(size_t)gseq * 12 + t] = ent;
          o_lp [(size_t)gseq * 12 + t] = blp;
          o_msk[(size_t)gseq * 13 + t + 1] = act ? 1.f : 0.f;
        }
        // parent & sibling from packed tokens
        int np0, np1;
        if (tok < 8) { np0 = tok; np1 = -1; }
        else {
          int c = 0, p0 = -1, p1 = -1;
          for (int i = t; i >= 0; --i) {
            int tk = (int)((pack >> (4 * i)) & 15u);
            c += (tk < 4 ? 2 : (tk < 8 ? 1 : 0)) - 1;
            if (c == 0 && p0 < 0) {
              p0 = tk;
              p1 = (i < t) ? (int)((pack >> (4 * (i + 1))) & 15u) : -1;
            }
          }
          np0 = p0; np1 = p1;
        }
        ps0_s[seq] = np0; ps1_s[seq] = np1;
      }
    }
    __syncthreads();

    if (t < MSTEPS - 1) {
      // ---- epilogue: h_next = tanh((xw + z) + b), write to hs ----
      float hnew[4][8];
      #pragma unroll
      for (int s = 0; s < 4; ++s) {
        const int sq = srow + s;
        const int p0 = ps0_s[sq], p1 = ps1_s[sq];
        float av[8], cv[8];
        #pragma unroll
        for (int c = 0; c < 8; ++c) { av[c] = 0.f; cv[c] = 0.f; }
        if (p0 >= 0) {
          float4 u0 = *(const float4*)&Wx[p0 * HID + cbase];
          float4 u1 = *(const float4*)&Wx[p0 * HID + cbase + 4];
          av[0]=u0.x; av[1]=u0.y; av[2]=u0.z; av[3]=u0.w;
          av[4]=u1.x; av[5]=u1.y; av[6]=u1.z; av[7]=u1.w;
        }
        if (p1 >= 0) {
          float4 u0 = *(const float4*)&Wx[(NTOK + p1) * HID + cbase];
          float4 u1 = *(const float4*)&Wx[(NTOK + p1) * HID + cbase + 4];
          cv[0]=u0.x; cv[1]=u0.y; cv[2]=u0.z; cv[3]=u0.w;
          cv[4]=u1.x; cv[5]=u1.y; cv[6]=u1.z; cv[7]=u1.w;
        }
        #pragma unroll
        for (int c = 0; c < 8; ++c) {
          float zz = t == 0 ? z1s[cbase + c]
                            : ((c & 1) ? acc2[s][c >> 1].y : acc2[s][c >> 1].x);
          hnew[s][c] = fast_tanh(((av[c] + cv[c]) + zz) + bb[c]);
        }
      }
      const int wbase = ((sg ^ cg) << 2);
      #pragma unroll
      for (int c = 0; c < 8; ++c) {
        *(float4*)&hs[(cbase + c) * SPB + wbase] =
            make_float4(hnew[0][c], hnew[1][c], hnew[2][c], hnew[3][c]);
      }
    }
    __syncthreads();
  }

  if (q == 0 && gseq < n) {
    o_cnt[gseq] = (float)cnt;
    o_len[gseq] = (float)lengths;
    #pragma unroll
    for (int j = 0; j < MSTEPS; ++j)
      o_seq[(size_t)gseq * 12 + j] = (float)((pack >> (4 * j)) & 15u);
  }
}

extern "C" void kernel_launch(void* const* d_in, const int* in_sizes, int n_in,
                              void* d_out, int out_size, void* d_ws, size_t ws_size,
                              hipStream_t stream) {
  const float* x0 = (const float*)d_in[1];
  const float* h0 = (const float*)d_in[2];
  const float* Wx = (const float*)d_in[3];
  const float* Wh = (const float*)d_in[4];
  const float* bv = (const float*)d_in[5];
  const float* Wp = (const float*)d_in[6];
  const float* bp = (const float*)d_in[7];
  float* out = (float*)d_out;

  int n = out_size / 51;   // 12+12+12+1+1+13 floats per sequence

  // jax.random.split(jax.random.key(42), 12), partitionable threefry:
  // keys[t] = threefry((0,42), (0, t)).
  KeyArr ka;
  for (int t = 0; t < 12; ++t) {
    uint32_t o0, o1;
    tf2x32(0u, 42u, 0u, (uint32_t)t, o0, o1);
    ka.k0[t] = o0; ka.k1[t] = o1;
  }

  int blocks = (n + SPB - 1) / SPB;
  eq_sampler<<<blocks, TPB, 0, stream>>>(x0, h0, Wx, Wh, bv, Wp, bp, out, n, ka);
}

// Round 11
// 472.295 us; speedup vs baseline: 1.1129x; 1.0225x over previous
//
#include <hip/hip_runtime.h>
#include <cstdint>
#include <cstddef>

#define NTOK   16
#define MSTEPS 12
#define HID    128
#define INSZ   32
#define SPB    64     // sequences per block (16 per wave)
#define TPB    256    // threads per block (4 waves)

typedef float f32x2 __attribute__((ext_vector_type(2)));

struct KeyArr { uint32_t k0[MSTEPS]; uint32_t k1[MSTEPS]; };

__host__ __device__ static inline uint32_t rotl32(uint32_t x, uint32_t d) {
  return (x << d) | (x >> (32u - d));
}

// Exact replica of JAX's threefry2x32 block cipher.
__host__ __device__ static inline void tf2x32(uint32_t k0, uint32_t k1,
                                              uint32_t x0, uint32_t x1,
                                              uint32_t &o0, uint32_t &o1) {
  const uint32_t ks2 = k0 ^ k1 ^ 0x1BD11BDAu;
  x0 += k0; x1 += k1;
  x0 += x1; x1 = rotl32(x1, 13); x1 ^= x0;
  x0 += x1; x1 = rotl32(x1, 15); x1 ^= x0;
  x0 += x1; x1 = rotl32(x1, 26); x1 ^= x0;
  x0 += x1; x1 = rotl32(x1,  6); x1 ^= x0;
  x0 += k1; x1 += ks2 + 1u;
  x0 += x1; x1 = rotl32(x1, 17); x1 ^= x0;
  x0 += x1; x1 = rotl32(x1, 29); x1 ^= x0;
  x0 += x1; x1 = rotl32(x1, 16); x1 ^= x0;
  x0 += x1; x1 = rotl32(x1, 24); x1 ^= x0;
  x0 += ks2; x1 += k0 + 2u;
  x0 += x1; x1 = rotl32(x1, 13); x1 ^= x0;
  x0 += x1; x1 = rotl32(x1, 15); x1 ^= x0;
  x0 += x1; x1 = rotl32(x1, 26); x1 ^= x0;
  x0 += x1; x1 = rotl32(x1,  6); x1 ^= x0;
  x0 += k0; x1 += k1 + 3u;
  x0 += x1; x1 = rotl32(x1, 17); x1 ^= x0;
  x0 += x1; x1 = rotl32(x1, 29); x1 ^= x0;
  x0 += x1; x1 = rotl32(x1, 16); x1 ^= x0;
  x0 += x1; x1 = rotl32(x1, 24); x1 ^= x0;
  x0 += k1; x1 += ks2 + 4u;
  x0 += x1; x1 = rotl32(x1, 13); x1 ^= x0;
  x0 += x1; x1 = rotl32(x1, 15); x1 ^= x0;
  x0 += x1; x1 = rotl32(x1, 26); x1 ^= x0;
  x0 += x1; x1 = rotl32(x1,  6); x1 ^= x0;
  x0 += ks2; x1 += k0 + 5u;
  o0 = x0; o1 = x1;
}

// Fast transcendentals on the HW pipes (v_exp_f32 / v_log_f32 / v_rcp_f32).
__device__ __forceinline__ float fast_exp(float x) { return __expf(x); }
__device__ __forceinline__ float fast_log(float x) { return __logf(x); }
__device__ __forceinline__ float fast_tanh(float x) {
  float ax = fabsf(x);
  float e  = __expf(2.0f * ax);
  float r  = fmaf(-2.0f, __builtin_amdgcn_rcpf(e + 1.0f), 1.0f);
  return copysignf(r, x);
}

// Packed f32x2 FMA — per-element semantics == fmaf (bit-identical chains).
__device__ __forceinline__ f32x2 pkfma(f32x2 a, f32x2 b, f32x2 c) {
  return __builtin_elementwise_fma(a, b, c);
}

// In-wave LDS write->read ordering (no block barrier needed): drain lgkm and
// stop the compiler from moving LDS ops across.
#define WAVE_LDS_FENCE() asm volatile("s_waitcnt lgkmcnt(0)" ::: "memory")

// Wave-autonomous: each wave owns 16 sequences end-to-end. No __syncthreads
// in the step loop. Per-wave h tile hsw[wv][k][16], chunk-swizzled:
// chunk(sgl,k) = sgl ^ ((k>>3)&3). GEMM reads (fixed k) are 4-address
// broadcasts (conflict-free); epilogue column writes alias 16 banks (accepted).
__global__ __launch_bounds__(TPB)
void eq_sampler(const float* __restrict__ x0in, const float* __restrict__ h0in,
                const float* __restrict__ Wx,   const float* __restrict__ Wh,
                const float* __restrict__ bvec, const float* __restrict__ Wp,
                const float* __restrict__ bp,   float* __restrict__ out,
                int n, KeyArr keys)
{
  __shared__ float hsw[4][HID][16];   // 32 KB, per-wave h tiles
  __shared__ float lgsw[4][16][17];   // per-wave staged raw logits
  __shared__ float h1s[HID];          // shared h_1 (identical across seqs)
  __shared__ float z1s[HID];          // shared h_1 @ Wh
  __shared__ float lgs0[NTOK];        // shared logits_0 (raw)
  __shared__ int   ps0w[4][16], ps1w[4][16];

  const int tid   = threadIdx.x;
  const int wv    = tid >> 6, lane = tid & 63;
  const int sgl   = lane & 3,  cgl = lane >> 2;   // GEMM: 4 seqs x 8 cols
  const int srow  = sgl * 4,   cbase = cgl * 8;   // wave-local seq row / col
  const int wsq   = lane >> 2, q = lane & 3;      // sampler: seq, quad-slot
  const int gbase = blockIdx.x * SPB + wv * 16;
  const int gseq  = gbase + wsq;                  // sampler's sequence
  const float TINY = 1.17549435e-38f;
  float* hb = &hsw[wv][0][0];

  // ---- prologue A: h_1 = tanh(x0@Wx + h0@Wh + b) — identical for all seqs --
  if (tid < HID) {
    float xw = 0.f;
    for (int k = 0; k < INSZ; ++k) xw = fmaf(x0in[k], Wx[k * HID + tid], xw);
    float a = 0.f;
    for (int k = 0; k < HID; ++k)  a = fmaf(h0in[k], Wh[k * HID + tid], a);
    h1s[tid] = fast_tanh((xw + a) + bvec[tid]);
  }
  __syncthreads();
  // ---- prologue B: z1 = h1@Wh (shared), logits0 = h1@Wp (shared) ----
  if (tid < HID) {
    float a = 0.f;
    for (int k = 0; k < HID; ++k) a = fmaf(h1s[k], Wh[k * HID + tid], a);
    z1s[tid] = a;
  } else if (tid < HID + NTOK) {
    const int j = tid - HID;
    float a = 0.f;
    for (int k = 0; k < HID; ++k) a = fmaf(h1s[k], Wp[k * NTOK + j], a);
    lgs0[j] = a;
  }
  __syncthreads();   // z1s/lgs0 published; no block barriers after this point

  float bb[8], bpv[4];
  #pragma unroll
  for (int c = 0; c < 8; ++c) bb[c] = bvec[cbase + c];
  #pragma unroll
  for (int j = 0; j < 4; ++j) bpv[j] = bp[q * 4 + j];

  // per-seq state (replicated in all 4 threads of a quad)
  int cnt = 1, lengths = 1;
  bool act = true, hasvar = false;
  uint64_t pack = 0;

  float* o_seq = out;
  float* o_ent = out + (size_t)n * 12;
  float* o_lp  = out + (size_t)n * 24;
  float* o_cnt = out + (size_t)n * 36;
  float* o_len = out + (size_t)n * 37;
  float* o_msk = out + (size_t)n * 38;

  if (q == 0 && gseq < n) o_msk[(size_t)gseq * 13] = 1.0f;

  f32x2 acc2[4][4];   // [seq][col-pair]
  f32x2 accP2[2];     // logits col: seq-pairs (0,1) and (2,3)

  for (int t = 0; t < MSTEPS; ++t) {
    if (t > 0) {
      // ---- fused GEMM: h_cur @ [Wh | Wp-col(cgl)], packed f32x2 FMA ----
      #pragma unroll
      for (int s = 0; s < 4; ++s) {
        #pragma unroll
        for (int c = 0; c < 4; ++c) acc2[s][c] = (f32x2){0.f, 0.f};
      }
      accP2[0] = (f32x2){0.f, 0.f};
      accP2[1] = (f32x2){0.f, 0.f};
      #pragma unroll 1
      for (int oct = 0; oct < 16; ++oct) {
        const int kb = oct * 8;
        const int hw = kb * 16 + ((sgl ^ (oct & 3)) << 2);   // word offset
        const float* wo = Wh + (size_t)kb * HID + cbase;
        const float* po = Wp + kb * NTOK + cgl;
        #pragma unroll
        for (int kk = 0; kk < 8; ++kk) {
          float4 h4 = *(const float4*)&hb[hw + kk * 16];
          float4 w0 = *(const float4*)(wo + kk * HID);
          float4 w1 = *(const float4*)(wo + kk * HID + 4);
          float  pw = po[kk * NTOK];
          const f32x2 wA = {w0.x, w0.y}, wB = {w0.z, w0.w};
          const f32x2 wC = {w1.x, w1.y}, wD = {w1.z, w1.w};
          const f32x2 pw2 = {pw, pw};
          #pragma unroll
          for (int s = 0; s < 4; ++s) {
            const float hv = s == 0 ? h4.x : s == 1 ? h4.y : s == 2 ? h4.z : h4.w;
            const f32x2 hv2 = {hv, hv};
            acc2[s][0] = pkfma(hv2, wA, acc2[s][0]);
            acc2[s][1] = pkfma(hv2, wB, acc2[s][1]);
            acc2[s][2] = pkfma(hv2, wC, acc2[s][2]);
            acc2[s][3] = pkfma(hv2, wD, acc2[s][3]);
          }
          accP2[0] = pkfma((f32x2){h4.x, h4.y}, pw2, accP2[0]);
          accP2[1] = pkfma((f32x2){h4.z, h4.w}, pw2, accP2[1]);
        }
      }
      // stage raw logits (same values/order as before)
      lgsw[wv][srow + 0][cgl] = accP2[0].x;
      lgsw[wv][srow + 1][cgl] = accP2[0].y;
      lgsw[wv][srow + 2][cgl] = accP2[1].x;
      lgsw[wv][srow + 3][cgl] = accP2[1].y;
    }
    WAVE_LDS_FENCE();

    // ---- sampling: 4 threads per seq, 4 tokens each (round-10 bit-orders) --
    {
      float lg[4];
      if (t == 0) {
        #pragma unroll
        for (int j = 0; j < 4; ++j) lg[j] = lgs0[q * 4 + j];
      } else {
        #pragma unroll
        for (int j = 0; j < 4; ++j) lg[j] = lgsw[wv][wsq][q * 4 + j];
      }
      #pragma unroll
      for (int j = 0; j < 4; ++j) lg[j] += bpv[j];

      // max over 16 (exact, order-free)
      float m4 = lg[0];
      #pragma unroll
      for (int j = 1; j < 4; ++j) m4 = fmaxf(m4, lg[j]);
      float mm = fmaxf(m4, __shfl_xor(m4, 1));
      mm = fmaxf(mm, __shfl_xor(mm, 2));

      float e[4]; float Zp = 0.f;
      #pragma unroll
      for (int j = 0; j < 4; ++j) { e[j] = fast_exp(lg[j] - mm); Zp += e[j]; }
      float Z = Zp + __shfl_xor(Zp, 1);
      Z += __shfl_xor(Z, 2);

      const int cntv = cnt;
      const int cl   = cntv + t;
      const int hasv = hasvar ? 1 : 0;

      float pr[4]; float Sp = 0.f;
      #pragma unroll
      for (int j = 0; j < 4; ++j) {
        const int tj = q * 4 + j;
        float p = e[j] / Z;
        if (tj >= 8 && cl < 2)                p = 0.f;
        if (tj <  8 && cl > MSTEPS - 2)       p = 0.f;
        if (tj == 8 && cntv == 1 && !hasv)    p = 0.f;
        pr[j] = p; Sp += p;
      }
      float S = Sp + __shfl_xor(Sp, 1);
      S += __shfl_xor(S, 2);

      float bs = 0.f, blp = 0.f, ep = 0.f; int bj = 0;
      #pragma unroll
      for (int j = 0; j < 4; ++j) {
        const int tj = q * 4 + j;
        float p = pr[j] / S;
        bool pos = p > 0.f;
        float lgpj = pos ? fast_log(p) : -__builtin_inff();
        ep += pos ? p * lgpj : 0.f;
        uint32_t b1, b2;
        tf2x32(keys.k0[t], keys.k1[t], 0u,
               (uint32_t)gseq * 16u + (uint32_t)tj, b1, b2);
        uint32_t bits = b1 ^ b2;
        float uf = __uint_as_float((bits >> 9) | 0x3F800000u) - 1.0f;
        uf += TINY; uf = fmaxf(TINY, uf);
        float g = -fast_log(-fast_log(uf));
        float sc = lgpj + g;
        if (j == 0) { bs = sc; bj = tj; blp = lgpj; }
        else if (sc > bs) { bs = sc; bj = tj; blp = lgpj; }
      }
      // argmax tree, lowest-index-on-tie preserved
      {
        float obs  = __shfl_xor(bs, 1);
        int   obj  = __shfl_xor(bj, 1);
        float oblp = __shfl_xor(blp, 1);
        if (obs > bs || (obs == bs && obj < bj)) { bs = obs; bj = obj; blp = oblp; }
      }
      {
        float obs  = __shfl_xor(bs, 2);
        int   obj  = __shfl_xor(bj, 2);
        float oblp = __shfl_xor(blp, 2);
        if (obs > bs || (obs == bs && obj < bj)) { bs = obs; bj = obj; blp = oblp; }
      }
      float ept = ep + __shfl_xor(ep, 1);
      ept += __shfl_xor(ept, 2);
      float ent = -ept;
      const int tok = bj;

      // state update (all 4 quad threads, identically)
      cnt += -1 + (tok < 4 ? 2 : (tok < 8 ? 1 : 0));
      act = act && (cnt > 0);
      lengths += act ? 1 : 0;
      if (tok >= 9) hasvar = true;
      pack |= (uint64_t)(uint32_t)tok << (4 * t);

      if (q == 0) {
        if (gseq < n) {
          o_ent[(size_t)gseq * 12 + t] = ent;
          o_lp [(size_t)gseq * 12 + t] = blp;
          o_msk[(size_t)gseq * 13 + t + 1] = act ? 1.f : 0.f;
        }
        // parent & sibling from packed tokens
        int np0, np1;
        if (tok < 8) { np0 = tok; np1 = -1; }
        else {
          int c = 0, p0 = -1, p1 = -1;
          for (int i = t; i >= 0; --i) {
            int tk = (int)((pack >> (4 * i)) & 15u);
            c += (tk < 4 ? 2 : (tk < 8 ? 1 : 0)) - 1;
            if (c == 0 && p0 < 0) {
              p0 = tk;
              p1 = (i < t) ? (int)((pack >> (4 * (i + 1))) & 15u) : -1;
            }
          }
          np0 = p0; np1 = p1;
        }
        ps0w[wv][wsq] = np0; ps1w[wv][wsq] = np1;
      }
    }
    WAVE_LDS_FENCE();

    if (t < MSTEPS - 1) {
      // ---- epilogue: h_next = tanh((xw + z) + b), write to own wave tile ----
      float hnew[4][8];
      #pragma unroll
      for (int s = 0; s < 4; ++s) {
        const int sq = srow + s;
        const int p0 = ps0w[wv][sq], p1 = ps1w[wv][sq];
        float av[8], cv[8];
        #pragma unroll
        for (int c = 0; c < 8; ++c) { av[c] = 0.f; cv[c] = 0.f; }
        if (p0 >= 0) {
          float4 u0 = *(const float4*)&Wx[p0 * HID + cbase];
          float4 u1 = *(const float4*)&Wx[p0 * HID + cbase + 4];
          av[0]=u0.x; av[1]=u0.y; av[2]=u0.z; av[3]=u0.w;
          av[4]=u1.x; av[5]=u1.y; av[6]=u1.z; av[7]=u1.w;
        }
        if (p1 >= 0) {
          float4 u0 = *(const float4*)&Wx[(NTOK + p1) * HID + cbase];
          float4 u1 = *(const float4*)&Wx[(NTOK + p1) * HID + cbase + 4];
          cv[0]=u0.x; cv[1]=u0.y; cv[2]=u0.z; cv[3]=u0.w;
          cv[4]=u1.x; cv[5]=u1.y; cv[6]=u1.z; cv[7]=u1.w;
        }
        #pragma unroll
        for (int c = 0; c < 8; ++c) {
          float zz = t == 0 ? z1s[cbase + c]
                            : ((c & 1) ? acc2[s][c >> 1].y : acc2[s][c >> 1].x);
          hnew[s][c] = fast_tanh(((av[c] + cv[c]) + zz) + bb[c]);
        }
      }
      #pragma unroll
      for (int c = 0; c < 8; ++c) {
        const int col = cbase + c;
        const int wb  = col * 16 + ((sgl ^ ((col >> 3) & 3)) << 2);
        *(float4*)&hb[wb] =
            make_float4(hnew[0][c], hnew[1][c], hnew[2][c], hnew[3][c]);
      }
    }
    WAVE_LDS_FENCE();
  }

  if (q == 0 && gseq < n) {
    o_cnt[gseq] = (float)cnt;
    o_len[gseq] = (float)lengths;
    #pragma unroll
    for (int j = 0; j < MSTEPS; ++j)
      o_seq[(size_t)gseq * 12 + j] = (float)((pack >> (4 * j)) & 15u);
  }
}

extern "C" void kernel_launch(void* const* d_in, const int* in_sizes, int n_in,
                              void* d_out, int out_size, void* d_ws, size_t ws_size,
                              hipStream_t stream) {
  const float* x0 = (const float*)d_in[1];
  const float* h0 = (const float*)d_in[2];
  const float* Wx = (const float*)d_in[3];
  const float* Wh = (const float*)d_in[4];
  const float* bv = (const float*)d_in[5];
  const float* Wp = (const float*)d_in[6];
  const float* bp = (const float*)d_in[7];
  float* out = (float*)d_out;

  int n = out_size / 51;   // 12+12+12+1+1+13 floats per sequence

  // jax.random.split(jax.random.key(42), 12), partitionable threefry:
  // keys[t] = threefry((0,42), (0, t)).
  KeyArr ka;
  for (int t = 0; t < 12; ++t) {
    uint32_t o0, o1;
    tf2x32(0u, 42u, 0u, (uint32_t)t, o0, o1);
    ka.k0[t] = o0; ka.k1[t] = o1;
  }

  int blocks = (n + SPB - 1) / SPB;
  eq_sampler<<<blocks, TPB, 0, stream>>>(x0, h0, Wx, Wh, bv, Wp, bp, out, n, ka);
}

// Round 13
// 469.679 us; speedup vs baseline: 1.1191x; 1.0056x over previous
//
#include <hip/hip_runtime.h>
#include <cstdint>
#include <cstddef>

#define NTOK   16
#define MSTEPS 12
#define HID    128
#define INSZ   32
#define SPB    64     // sequences per block (16 per wave)
#define TPB    256    // threads per block (4 waves)

typedef float f32x2 __attribute__((ext_vector_type(2)));

struct KeyArr { uint32_t k0[MSTEPS]; uint32_t k1[MSTEPS]; };

__host__ __device__ static inline uint32_t rotl32(uint32_t x, uint32_t d) {
  return (x << d) | (x >> (32u - d));
}

// Exact replica of JAX's threefry2x32 block cipher.
__host__ __device__ static inline void tf2x32(uint32_t k0, uint32_t k1,
                                              uint32_t x0, uint32_t x1,
                                              uint32_t &o0, uint32_t &o1) {
  const uint32_t ks2 = k0 ^ k1 ^ 0x1BD11BDAu;
  x0 += k0; x1 += k1;
  x0 += x1; x1 = rotl32(x1, 13); x1 ^= x0;
  x0 += x1; x1 = rotl32(x1, 15); x1 ^= x0;
  x0 += x1; x1 = rotl32(x1, 26); x1 ^= x0;
  x0 += x1; x1 = rotl32(x1,  6); x1 ^= x0;
  x0 += k1; x1 += ks2 + 1u;
  x0 += x1; x1 = rotl32(x1, 17); x1 ^= x0;
  x0 += x1; x1 = rotl32(x1, 29); x1 ^= x0;
  x0 += x1; x1 = rotl32(x1, 16); x1 ^= x0;
  x0 += x1; x1 = rotl32(x1, 24); x1 ^= x0;
  x0 += ks2; x1 += k0 + 2u;
  x0 += x1; x1 = rotl32(x1, 13); x1 ^= x0;
  x0 += x1; x1 = rotl32(x1, 15); x1 ^= x0;
  x0 += x1; x1 = rotl32(x1, 26); x1 ^= x0;
  x0 += x1; x1 = rotl32(x1,  6); x1 ^= x0;
  x0 += k0; x1 += k1 + 3u;
  x0 += x1; x1 = rotl32(x1, 17); x1 ^= x0;
  x0 += x1; x1 = rotl32(x1, 29); x1 ^= x0;
  x0 += x1; x1 = rotl32(x1, 16); x1 ^= x0;
  x0 += x1; x1 = rotl32(x1, 24); x1 ^= x0;
  x0 += k1; x1 += ks2 + 4u;
  x0 += x1; x1 = rotl32(x1, 13); x1 ^= x0;
  x0 += x1; x1 = rotl32(x1, 15); x1 ^= x0;
  x0 += x1; x1 = rotl32(x1, 26); x1 ^= x0;
  x0 += x1; x1 = rotl32(x1,  6); x1 ^= x0;
  x0 += ks2; x1 += k0 + 5u;
  o0 = x0; o1 = x1;
}

// Fast transcendentals on the HW pipes (v_exp_f32 / v_log_f32 / v_rcp_f32).
__device__ __forceinline__ float fast_exp(float x) { return __expf(x); }
__device__ __forceinline__ float fast_log(float x) { return __logf(x); }
__device__ __forceinline__ float fast_tanh(float x) {
  float ax = fabsf(x);
  float e  = __expf(2.0f * ax);
  float r  = fmaf(-2.0f, __builtin_amdgcn_rcpf(e + 1.0f), 1.0f);
  return copysignf(r, x);
}

// Forced packed FMA with in-pair broadcast (all operands are legal 64-bit
// VGPR pairs). SEL0: both result elements read src0's LO half; SEL1: HI half.
// Per-element semantics == fmaf, chains identical to the scalar form.
#define PKFMA_SEL0(accv, hpair, wv)                                          \
  asm("v_pk_fma_f32 %0, %1, %2, %0 op_sel:[0,0,0] op_sel_hi:[0,1,1]"         \
      : "+v"(accv) : "v"(hpair), "v"(wv))
#define PKFMA_SEL1(accv, hpair, wv)                                          \
  asm("v_pk_fma_f32 %0, %1, %2, %0 op_sel:[1,0,0] op_sel_hi:[1,1,1]"         \
      : "+v"(accv) : "v"(hpair), "v"(wv))

// In-wave LDS write->read ordering (no block barrier needed).
#define WAVE_LDS_FENCE() asm volatile("s_waitcnt lgkmcnt(0)" ::: "memory")

// Wave-autonomous: each wave owns 16 sequences end-to-end. No __syncthreads
// in the step loop. Per-wave h tile hsw[wv][k][16], chunk-swizzled.
__global__ __launch_bounds__(TPB)
void eq_sampler(const float* __restrict__ x0in, const float* __restrict__ h0in,
                const float* __restrict__ Wx,   const float* __restrict__ Wh,
                const float* __restrict__ bvec, const float* __restrict__ Wp,
                const float* __restrict__ bp,   float* __restrict__ out,
                int n, KeyArr keys)
{
  __shared__ float hsw[4][HID][16];   // 32 KB, per-wave h tiles
  __shared__ float lgsw[4][16][17];   // per-wave staged raw logits
  __shared__ float h1s[HID];          // shared h_1 (identical across seqs)
  __shared__ float z1s[HID];          // shared h_1 @ Wh
  __shared__ float lgs0[NTOK];        // shared logits_0 (raw)
  __shared__ int   ps0w[4][16], ps1w[4][16];

  const int tid   = threadIdx.x;
  const int wv    = tid >> 6, lane = tid & 63;
  const int sgl   = lane & 3,  cgl = lane >> 2;   // GEMM: 4 seqs x 8 cols
  const int srow  = sgl * 4,   cbase = cgl * 8;   // wave-local seq row / col
  const int wsq   = lane >> 2, q = lane & 3;      // sampler: seq, quad-slot
  const int gbase = blockIdx.x * SPB + wv * 16;
  const int gseq  = gbase + wsq;                  // sampler's sequence
  const float TINY = 1.17549435e-38f;
  float* hb = &hsw[wv][0][0];

  // ---- prologue A: h_1 = tanh(x0@Wx + h0@Wh + b) — identical for all seqs --
  if (tid < HID) {
    float xw = 0.f;
    for (int k = 0; k < INSZ; ++k) xw = fmaf(x0in[k], Wx[k * HID + tid], xw);
    float a = 0.f;
    for (int k = 0; k < HID; ++k)  a = fmaf(h0in[k], Wh[k * HID + tid], a);
    h1s[tid] = fast_tanh((xw + a) + bvec[tid]);
  }
  __syncthreads();
  // ---- prologue B: z1 = h1@Wh (shared), logits0 = h1@Wp (shared) ----
  if (tid < HID) {
    float a = 0.f;
    for (int k = 0; k < HID; ++k) a = fmaf(h1s[k], Wh[k * HID + tid], a);
    z1s[tid] = a;
  } else if (tid < HID + NTOK) {
    const int j = tid - HID;
    float a = 0.f;
    for (int k = 0; k < HID; ++k) a = fmaf(h1s[k], Wp[k * NTOK + j], a);
    lgs0[j] = a;
  }
  __syncthreads();   // z1s/lgs0 published; no block barriers after this point

  float bb[8], bpv[4];
  #pragma unroll
  for (int c = 0; c < 8; ++c) bb[c] = bvec[cbase + c];
  #pragma unroll
  for (int j = 0; j < 4; ++j) bpv[j] = bp[q * 4 + j];

  // per-seq state (replicated in all 4 threads of a quad)
  int cnt = 1, lengths = 1;
  bool act = true, hasvar = false;
  uint64_t pack = 0;

  float* o_seq = out;
  float* o_ent = out + (size_t)n * 12;
  float* o_lp  = out + (size_t)n * 24;
  float* o_cnt = out + (size_t)n * 36;
  float* o_len = out + (size_t)n * 37;
  float* o_msk = out + (size_t)n * 38;

  if (q == 0 && gseq < n) o_msk[(size_t)gseq * 13] = 1.0f;

  f32x2 acc2[4][4];   // [seq][col-pair]
  float accP[4];      // logits col, one chain per seq (scalar fmaf)

  for (int t = 0; t < MSTEPS; ++t) {
    if (t > 0) {
      // ---- fused GEMM: h_cur @ [Wh | Wp-col(cgl)], forced v_pk_fma_f32 ----
      #pragma unroll
      for (int s = 0; s < 4; ++s) {
        accP[s] = 0.f;
        #pragma unroll
        for (int c = 0; c < 4; ++c) acc2[s][c] = (f32x2){0.f, 0.f};
      }
      #pragma unroll 1
      for (int oct = 0; oct < 16; ++oct) {
        const int kb = oct * 8;
        const int hw = kb * 16 + ((sgl ^ (oct & 3)) << 2);   // word offset
        const float* wo = Wh + (size_t)kb * HID + cbase;
        const float* po = Wp + kb * NTOK + cgl;
        #pragma unroll
        for (int kk = 0; kk < 8; ++kk) {
          float4 h4 = *(const float4*)&hb[hw + kk * 16];
          float4 w0 = *(const float4*)(wo + kk * HID);
          float4 w1 = *(const float4*)(wo + kk * HID + 4);
          float  pw = po[kk * NTOK];
          f32x2 hp0 = {h4.x, h4.y};
          f32x2 hp1 = {h4.z, h4.w};
          const f32x2* wp0 = (const f32x2*)&w0;   // {x,y},{z,w}
          const f32x2* wp1 = (const f32x2*)&w1;
          // s=0: broadcast h4.x (lo of hp0); s=1: h4.y (hi of hp0); etc.
          PKFMA_SEL0(acc2[0][0], hp0, wp0[0]);
          PKFMA_SEL0(acc2[0][1], hp0, wp0[1]);
          PKFMA_SEL0(acc2[0][2], hp0, wp1[0]);
          PKFMA_SEL0(acc2[0][3], hp0, wp1[1]);
          PKFMA_SEL1(acc2[1][0], hp0, wp0[0]);
          PKFMA_SEL1(acc2[1][1], hp0, wp0[1]);
          PKFMA_SEL1(acc2[1][2], hp0, wp1[0]);
          PKFMA_SEL1(acc2[1][3], hp0, wp1[1]);
          PKFMA_SEL0(acc2[2][0], hp1, wp0[0]);
          PKFMA_SEL0(acc2[2][1], hp1, wp0[1]);
          PKFMA_SEL0(acc2[2][2], hp1, wp1[0]);
          PKFMA_SEL0(acc2[2][3], hp1, wp1[1]);
          PKFMA_SEL1(acc2[3][0], hp1, wp0[0]);
          PKFMA_SEL1(acc2[3][1], hp1, wp0[1]);
          PKFMA_SEL1(acc2[3][2], hp1, wp1[0]);
          PKFMA_SEL1(acc2[3][3], hp1, wp1[1]);
          // logits column: scalar chains (identical per-seq order)
          accP[0] = fmaf(h4.x, pw, accP[0]);
          accP[1] = fmaf(h4.y, pw, accP[1]);
          accP[2] = fmaf(h4.z, pw, accP[2]);
          accP[3] = fmaf(h4.w, pw, accP[3]);
        }
      }
      // stage raw logits (same values/order as before)
      lgsw[wv][srow + 0][cgl] = accP[0];
      lgsw[wv][srow + 1][cgl] = accP[1];
      lgsw[wv][srow + 2][cgl] = accP[2];
      lgsw[wv][srow + 3][cgl] = accP[3];
    }
    WAVE_LDS_FENCE();

    // ---- sampling: 4 threads per seq, 4 tokens each (round-10 bit-orders) --
    {
      float lg[4];
      if (t == 0) {
        #pragma unroll
        for (int j = 0; j < 4; ++j) lg[j] = lgs0[q * 4 + j];
      } else {
        #pragma unroll
        for (int j = 0; j < 4; ++j) lg[j] = lgsw[wv][wsq][q * 4 + j];
      }
      #pragma unroll
      for (int j = 0; j < 4; ++j) lg[j] += bpv[j];

      // max over 16 (exact, order-free)
      float m4 = lg[0];
      #pragma unroll
      for (int j = 1; j < 4; ++j) m4 = fmaxf(m4, lg[j]);
      float mm = fmaxf(m4, __shfl_xor(m4, 1));
      mm = fmaxf(mm, __shfl_xor(mm, 2));

      float e[4]; float Zp = 0.f;
      #pragma unroll
      for (int j = 0; j < 4; ++j) { e[j] = fast_exp(lg[j] - mm); Zp += e[j]; }
      float Z = Zp + __shfl_xor(Zp, 1);
      Z += __shfl_xor(Z, 2);

      const int cntv = cnt;
      const int cl   = cntv + t;
      const int hasv = hasvar ? 1 : 0;

      float pr[4]; float Sp = 0.f;
      #pragma unroll
      for (int j = 0; j < 4; ++j) {
        const int tj = q * 4 + j;
        float p = e[j] / Z;
        if (tj >= 8 && cl < 2)                p = 0.f;
        if (tj <  8 && cl > MSTEPS - 2)       p = 0.f;
        if (tj == 8 && cntv == 1 && !hasv)    p = 0.f;
        pr[j] = p; Sp += p;
      }
      float S = Sp + __shfl_xor(Sp, 1);
      S += __shfl_xor(S, 2);

      float bs = 0.f, blp = 0.f, ep = 0.f; int bj = 0;
      #pragma unroll
      for (int j = 0; j < 4; ++j) {
        const int tj = q * 4 + j;
        float p = pr[j] / S;
        bool pos = p > 0.f;
        float lgpj = pos ? fast_log(p) : -__builtin_inff();
        ep += pos ? p * lgpj : 0.f;
        uint32_t b1, b2;
        tf2x32(keys.k0[t], keys.k1[t], 0u,
               (uint32_t)gseq * 16u + (uint32_t)tj, b1, b2);
        uint32_t bits = b1 ^ b2;
        float uf = __uint_as_float((bits >> 9) | 0x3F800000u) - 1.0f;
        uf += TINY; uf = fmaxf(TINY, uf);
        float g = -fast_log(-fast_log(uf));
        float sc = lgpj + g;
        if (j == 0) { bs = sc; bj = tj; blp = lgpj; }
        else if (sc > bs) { bs = sc; bj = tj; blp = lgpj; }
      }
      // argmax tree, lowest-index-on-tie preserved
      {
        float obs  = __shfl_xor(bs, 1);
        int   obj  = __shfl_xor(bj, 1);
        float oblp = __shfl_xor(blp, 1);
        if (obs > bs || (obs == bs && obj < bj)) { bs = obs; bj = obj; blp = oblp; }
      }
      {
        float obs  = __shfl_xor(bs, 2);
        int   obj  = __shfl_xor(bj, 2);
        float oblp = __shfl_xor(blp, 2);
        if (obs > bs || (obs == bs && obj < bj)) { bs = obs; bj = obj; blp = oblp; }
      }
      float ept = ep + __shfl_xor(ep, 1);
      ept += __shfl_xor(ept, 2);
      float ent = -ept;
      const int tok = bj;

      // state update (all 4 quad threads, identically)
      cnt += -1 + (tok < 4 ? 2 : (tok < 8 ? 1 : 0));
      act = act && (cnt > 0);
      lengths += act ? 1 : 0;
      if (tok >= 9) hasvar = true;
      pack |= (uint64_t)(uint32_t)tok << (4 * t);

      if (q == 0) {
        if (gseq < n) {
          o_ent[(size_t)gseq * 12 + t] = ent;
          o_lp [(size_t)gseq * 12 + t] = blp;
          o_msk[(size_t)gseq * 13 + t + 1] = act ? 1.f : 0.f;
        }
        // parent & sibling from packed tokens
        int np0, np1;
        if (tok < 8) { np0 = tok; np1 = -1; }
        else {
          int c = 0, p0 = -1, p1 = -1;
          for (int i = t; i >= 0; --i) {
            int tk = (int)((pack >> (4 * i)) & 15u);
            c += (tk < 4 ? 2 : (tk < 8 ? 1 : 0)) - 1;
            if (c == 0 && p0 < 0) {
              p0 = tk;
              p1 = (i < t) ? (int)((pack >> (4 * (i + 1))) & 15u) : -1;
            }
          }
          np0 = p0; np1 = p1;
        }
        ps0w[wv][wsq] = np0; ps1w[wv][wsq] = np1;
      }
    }
    WAVE_LDS_FENCE();

    if (t < MSTEPS - 1) {
      // ---- epilogue: h_next = tanh((xw + z) + b), write to own wave tile ----
      float hnew[4][8];
      #pragma unroll
      for (int s = 0; s < 4; ++s) {
        const int sq = srow + s;
        const int p0 = ps0w[wv][sq], p1 = ps1w[wv][sq];
        float av[8], cv[8];
        #pragma unroll
        for (int c = 0; c < 8; ++c) { av[c] = 0.f; cv[c] = 0.f; }
        if (p0 >= 0) {
          float4 u0 = *(const float4*)&Wx[p0 * HID + cbase];
          float4 u1 = *(const float4*)&Wx[p0 * HID + cbase + 4];
          av[0]=u0.x; av[1]=u0.y; av[2]=u0.z; av[3]=u0.w;
          av[4]=u1.x; av[5]=u1.y; av[6]=u1.z; av[7]=u1.w;
        }
        if (p1 >= 0) {
          float4 u0 = *(const float4*)&Wx[(NTOK + p1) * HID + cbase];
          float4 u1 = *(const float4*)&Wx[(NTOK + p1) * HID + cbase + 4];
          cv[0]=u0.x; cv[1]=u0.y; cv[2]=u0.z; cv[3]=u0.w;
          cv[4]=u1.x; cv[5]=u1.y; cv[6]=u1.z; cv[7]=u1.w;
        }
        #pragma unroll
        for (int c = 0; c < 8; ++c) {
          float zz = t == 0 ? z1s[cbase + c]
                            : ((c & 1) ? acc2[s][c >> 1].y : acc2[s][c >> 1].x);
          hnew[s][c] = fast_tanh(((av[c] + cv[c]) + zz) + bb[c]);
        }
      }
      #pragma unroll
      for (int c = 0; c < 8; ++c) {
        const int col = cbase + c;
        const int wb  = col * 16 + ((sgl ^ ((col >> 3) & 3)) << 2);
        *(float4*)&hb[wb] =
            make_float4(hnew[0][c], hnew[1][c], hnew[2][c], hnew[3][c]);
      }
    }
    WAVE_LDS_FENCE();
  }

  if (q == 0 && gseq < n) {
    o_cnt[gseq] = (float)cnt;
    o_len[gseq] = (float)lengths;
    #pragma unroll
    for (int j = 0; j < MSTEPS; ++j)
      o_seq[(size_t)gseq * 12 + j] = (float)((pack >> (4 * j)) & 15u);
  }
}

extern "C" void kernel_launch(void* const* d_in, const int* in_sizes, int n_in,
                              void* d_out, int out_size, void* d_ws, size_t ws_size,
                              hipStream_t stream) {
  const float* x0 = (const float*)d_in[1];
  const float* h0 = (const float*)d_in[2];
  const float* Wx = (const float*)d_in[3];
  const float* Wh = (const float*)d_in[4];
  const float* bv = (const float*)d_in[5];
  const float* Wp = (const float*)d_in[6];
  const float* bp = (const float*)d_in[7];
  float* out = (float*)d_out;

  int n = out_size / 51;   // 12+12+12+1+1+13 floats per sequence

  // jax.random.split(jax.random.key(42), 12), partitionable threefry:
  // keys[t] = threefry((0,42), (0, t)).
  KeyArr ka;
  for (int t = 0; t < 12; ++t) {
    uint32_t o0, o1;
    tf2x32(0u, 42u, 0u, (uint32_t)t, o0, o1);
    ka.k0[t] = o0; ka.k1[t] = o1;
  }

  int blocks = (n + SPB - 1) / SPB;
  eq_sampler<<<blocks, TPB, 0, stream>>>(x0, h0, Wx, Wh, bv, Wp, bp, out, n, ka);
}

// Round 14
// 458.803 us; speedup vs baseline: 1.1456x; 1.0237x over previous
//
#include <hip/hip_runtime.h>
#include <cstdint>
#include <cstddef>

#define NTOK   16
#define MSTEPS 12
#define HID    128
#define INSZ   32
#define SPB    64     // sequences per block (16 per wave)
#define TPB    256    // threads per block (4 waves)

typedef float f32x2 __attribute__((ext_vector_type(2)));

struct KeyArr { uint32_t k0[MSTEPS]; uint32_t k1[MSTEPS]; };

__host__ __device__ static inline uint32_t rotl32(uint32_t x, uint32_t d) {
  return (x << d) | (x >> (32u - d));
}

// Exact replica of JAX's threefry2x32 block cipher.
__host__ __device__ static inline void tf2x32(uint32_t k0, uint32_t k1,
                                              uint32_t x0, uint32_t x1,
                                              uint32_t &o0, uint32_t &o1) {
  const uint32_t ks2 = k0 ^ k1 ^ 0x1BD11BDAu;
  x0 += k0; x1 += k1;
  x0 += x1; x1 = rotl32(x1, 13); x1 ^= x0;
  x0 += x1; x1 = rotl32(x1, 15); x1 ^= x0;
  x0 += x1; x1 = rotl32(x1, 26); x1 ^= x0;
  x0 += x1; x1 = rotl32(x1,  6); x1 ^= x0;
  x0 += k1; x1 += ks2 + 1u;
  x0 += x1; x1 = rotl32(x1, 17); x1 ^= x0;
  x0 += x1; x1 = rotl32(x1, 29); x1 ^= x0;
  x0 += x1; x1 = rotl32(x1, 16); x1 ^= x0;
  x0 += x1; x1 = rotl32(x1, 24); x1 ^= x0;
  x0 += ks2; x1 += k0 + 2u;
  x0 += x1; x1 = rotl32(x1, 13); x1 ^= x0;
  x0 += x1; x1 = rotl32(x1, 15); x1 ^= x0;
  x0 += x1; x1 = rotl32(x1, 26); x1 ^= x0;
  x0 += x1; x1 = rotl32(x1,  6); x1 ^= x0;
  x0 += k0; x1 += k1 + 3u;
  x0 += x1; x1 = rotl32(x1, 17); x1 ^= x0;
  x0 += x1; x1 = rotl32(x1, 29); x1 ^= x0;
  x0 += x1; x1 = rotl32(x1, 16); x1 ^= x0;
  x0 += x1; x1 = rotl32(x1, 24); x1 ^= x0;
  x0 += k1; x1 += ks2 + 4u;
  x0 += x1; x1 = rotl32(x1, 13); x1 ^= x0;
  x0 += x1; x1 = rotl32(x1, 15); x1 ^= x0;
  x0 += x1; x1 = rotl32(x1, 26); x1 ^= x0;
  x0 += x1; x1 = rotl32(x1,  6); x1 ^= x0;
  x0 += ks2; x1 += k0 + 5u;
  o0 = x0; o1 = x1;
}

// Fast transcendentals on the HW pipes (v_exp_f32 / v_log_f32 / v_rcp_f32).
__device__ __forceinline__ float fast_exp(float x) { return __expf(x); }
__device__ __forceinline__ float fast_log(float x) { return __logf(x); }
__device__ __forceinline__ float fast_tanh(float x) {
  float ax = fabsf(x);
  float e  = __expf(2.0f * ax);
  float r  = fmaf(-2.0f, __builtin_amdgcn_rcpf(e + 1.0f), 1.0f);
  return copysignf(r, x);
}

// Forced packed FMA with in-pair broadcast (all operands are legal 64-bit
// VGPR pairs). SEL0: both result elements read src0's LO half; SEL1: HI half.
#define PKFMA_SEL0(accv, hpair, wv)                                          \
  asm("v_pk_fma_f32 %0, %1, %2, %0 op_sel:[0,0,0] op_sel_hi:[0,1,1]"         \
      : "+v"(accv) : "v"(hpair), "v"(wv))
#define PKFMA_SEL1(accv, hpair, wv)                                          \
  asm("v_pk_fma_f32 %0, %1, %2, %0 op_sel:[1,0,0] op_sel_hi:[1,1,1]"         \
      : "+v"(accv) : "v"(hpair), "v"(wv))

// In-wave LDS write->read ordering (no block barrier needed).
#define WAVE_LDS_FENCE() asm volatile("s_waitcnt lgkmcnt(0)" ::: "memory")

// Wave-autonomous: each wave owns 16 sequences end-to-end. No __syncthreads
// in the step loop. Per-wave h tile hsw[wv][k][16], chunk-swizzled.
__global__ __launch_bounds__(TPB)
void eq_sampler(const float* __restrict__ x0in, const float* __restrict__ h0in,
                const float* __restrict__ Wx,   const float* __restrict__ Wh,
                const float* __restrict__ bvec, const float* __restrict__ Wp,
                const float* __restrict__ bp,   float* __restrict__ out,
                int n, KeyArr keys)
{
  __shared__ float hsw[4][HID][16];   // 32 KB, per-wave h tiles
  __shared__ float lgsw[4][16][17];   // per-wave staged raw logits
  __shared__ float h1s[HID];          // shared h_1 (identical across seqs)
  __shared__ float z1s[HID];          // shared h_1 @ Wh
  __shared__ float lgs0[NTOK];        // shared logits_0 (raw)
  __shared__ int   ps0w[4][16], ps1w[4][16];

  const int tid   = threadIdx.x;
  const int wv    = tid >> 6, lane = tid & 63;
  const int sgl   = lane & 3,  cgl = lane >> 2;   // GEMM: 4 seqs x 8 cols
  const int srow  = sgl * 4,   cbase = cgl * 8;   // wave-local seq row / col
  const int wsq   = lane >> 2, q = lane & 3;      // sampler: seq, quad-slot
  const int gbase = blockIdx.x * SPB + wv * 16;
  const int gseq  = gbase + wsq;                  // sampler's sequence
  const float TINY = 1.17549435e-38f;
  float* hb = &hsw[wv][0][0];

  // ---- prologue A: h_1 = tanh(x0@Wx + h0@Wh + b) — identical for all seqs --
  if (tid < HID) {
    float xw = 0.f;
    for (int k = 0; k < INSZ; ++k) xw = fmaf(x0in[k], Wx[k * HID + tid], xw);
    float a = 0.f;
    for (int k = 0; k < HID; ++k)  a = fmaf(h0in[k], Wh[k * HID + tid], a);
    h1s[tid] = fast_tanh((xw + a) + bvec[tid]);
  }
  __syncthreads();
  // ---- prologue B: z1 = h1@Wh (shared), logits0 = h1@Wp (shared) ----
  if (tid < HID) {
    float a = 0.f;
    for (int k = 0; k < HID; ++k) a = fmaf(h1s[k], Wh[k * HID + tid], a);
    z1s[tid] = a;
  } else if (tid < HID + NTOK) {
    const int j = tid - HID;
    float a = 0.f;
    for (int k = 0; k < HID; ++k) a = fmaf(h1s[k], Wp[k * NTOK + j], a);
    lgs0[j] = a;
  }
  __syncthreads();   // z1s/lgs0 published; no block barriers after this point

  float bb[8], bpv[4];
  #pragma unroll
  for (int c = 0; c < 8; ++c) bb[c] = bvec[cbase + c];
  #pragma unroll
  for (int j = 0; j < 4; ++j) bpv[j] = bp[q * 4 + j];

  // per-seq state (replicated in all 4 threads of a quad)
  int cnt = 1, lengths = 1;
  bool act = true, hasvar = false;
  uint64_t pack = 0;

  float* o_seq = out;
  float* o_ent = out + (size_t)n * 12;
  float* o_lp  = out + (size_t)n * 24;
  float* o_cnt = out + (size_t)n * 36;
  float* o_len = out + (size_t)n * 37;
  float* o_msk = out + (size_t)n * 38;

  if (q == 0 && gseq < n) o_msk[(size_t)gseq * 13] = 1.0f;

  f32x2 acc2[4][4];   // [seq][col-pair]
  float accP[4];      // logits col, one chain per seq (scalar fmaf)

  for (int t = 0; t < MSTEPS; ++t) {
    if (t > 0) {
      // ---- fused GEMM: h_cur @ [Wh | Wp-col(cgl)], forced v_pk_fma_f32 ----
      // T5: bias the CU scheduler toward waves in their dense-FMA burst;
      // other waves on this SIMD are in cipher/scan/store phases
      // (wave-autonomous structure => role diversity exists).
      __builtin_amdgcn_s_setprio(1);
      #pragma unroll
      for (int s = 0; s < 4; ++s) {
        accP[s] = 0.f;
        #pragma unroll
        for (int c = 0; c < 4; ++c) acc2[s][c] = (f32x2){0.f, 0.f};
      }
      #pragma unroll 1
      for (int oct = 0; oct < 16; ++oct) {
        const int kb = oct * 8;
        const int hw = kb * 16 + ((sgl ^ (oct & 3)) << 2);   // word offset
        const float* wo = Wh + (size_t)kb * HID + cbase;
        const float* po = Wp + kb * NTOK + cgl;
        #pragma unroll
        for (int kk = 0; kk < 8; ++kk) {
          float4 h4 = *(const float4*)&hb[hw + kk * 16];
          float4 w0 = *(const float4*)(wo + kk * HID);
          float4 w1 = *(const float4*)(wo + kk * HID + 4);
          float  pw = po[kk * NTOK];
          f32x2 hp0 = {h4.x, h4.y};
          f32x2 hp1 = {h4.z, h4.w};
          const f32x2* wp0 = (const f32x2*)&w0;   // {x,y},{z,w}
          const f32x2* wp1 = (const f32x2*)&w1;
          // s=0: broadcast h4.x (lo of hp0); s=1: h4.y (hi of hp0); etc.
          PKFMA_SEL0(acc2[0][0], hp0, wp0[0]);
          PKFMA_SEL0(acc2[0][1], hp0, wp0[1]);
          PKFMA_SEL0(acc2[0][2], hp0, wp1[0]);
          PKFMA_SEL0(acc2[0][3], hp0, wp1[1]);
          PKFMA_SEL1(acc2[1][0], hp0, wp0[0]);
          PKFMA_SEL1(acc2[1][1], hp0, wp0[1]);
          PKFMA_SEL1(acc2[1][2], hp0, wp1[0]);
          PKFMA_SEL1(acc2[1][3], hp0, wp1[1]);
          PKFMA_SEL0(acc2[2][0], hp1, wp0[0]);
          PKFMA_SEL0(acc2[2][1], hp1, wp0[1]);
          PKFMA_SEL0(acc2[2][2], hp1, wp1[0]);
          PKFMA_SEL0(acc2[2][3], hp1, wp1[1]);
          PKFMA_SEL1(acc2[3][0], hp1, wp0[0]);
          PKFMA_SEL1(acc2[3][1], hp1, wp0[1]);
          PKFMA_SEL1(acc2[3][2], hp1, wp1[0]);
          PKFMA_SEL1(acc2[3][3], hp1, wp1[1]);
          // logits column: scalar chains (identical per-seq order)
          accP[0] = fmaf(h4.x, pw, accP[0]);
          accP[1] = fmaf(h4.y, pw, accP[1]);
          accP[2] = fmaf(h4.z, pw, accP[2]);
          accP[3] = fmaf(h4.w, pw, accP[3]);
        }
      }
      __builtin_amdgcn_s_setprio(0);
      // stage raw logits (same values/order as before)
      lgsw[wv][srow + 0][cgl] = accP[0];
      lgsw[wv][srow + 1][cgl] = accP[1];
      lgsw[wv][srow + 2][cgl] = accP[2];
      lgsw[wv][srow + 3][cgl] = accP[3];
    }
    WAVE_LDS_FENCE();

    // ---- sampling: 4 threads per seq, 4 tokens each (round-10 bit-orders) --
    {
      float lg[4];
      if (t == 0) {
        #pragma unroll
        for (int j = 0; j < 4; ++j) lg[j] = lgs0[q * 4 + j];
      } else {
        #pragma unroll
        for (int j = 0; j < 4; ++j) lg[j] = lgsw[wv][wsq][q * 4 + j];
      }
      #pragma unroll
      for (int j = 0; j < 4; ++j) lg[j] += bpv[j];

      // max over 16 (exact, order-free)
      float m4 = lg[0];
      #pragma unroll
      for (int j = 1; j < 4; ++j) m4 = fmaxf(m4, lg[j]);
      float mm = fmaxf(m4, __shfl_xor(m4, 1));
      mm = fmaxf(mm, __shfl_xor(mm, 2));

      float e[4]; float Zp = 0.f;
      #pragma unroll
      for (int j = 0; j < 4; ++j) { e[j] = fast_exp(lg[j] - mm); Zp += e[j]; }
      float Z = Zp + __shfl_xor(Zp, 1);
      Z += __shfl_xor(Z, 2);

      const int cntv = cnt;
      const int cl   = cntv + t;
      const int hasv = hasvar ? 1 : 0;

      float pr[4]; float Sp = 0.f;
      #pragma unroll
      for (int j = 0; j < 4; ++j) {
        const int tj = q * 4 + j;
        float p = e[j] / Z;
        if (tj >= 8 && cl < 2)                p = 0.f;
        if (tj <  8 && cl > MSTEPS - 2)       p = 0.f;
        if (tj == 8 && cntv == 1 && !hasv)    p = 0.f;
        pr[j] = p; Sp += p;
      }
      float S = Sp + __shfl_xor(Sp, 1);
      S += __shfl_xor(S, 2);

      float bs = 0.f, blp = 0.f, ep = 0.f; int bj = 0;
      #pragma unroll
      for (int j = 0; j < 4; ++j) {
        const int tj = q * 4 + j;
        float p = pr[j] / S;
        bool pos = p > 0.f;
        float lgpj = pos ? fast_log(p) : -__builtin_inff();
        ep += pos ? p * lgpj : 0.f;
        uint32_t b1, b2;
        tf2x32(keys.k0[t], keys.k1[t], 0u,
               (uint32_t)gseq * 16u + (uint32_t)tj, b1, b2);
        uint32_t bits = b1 ^ b2;
        float uf = __uint_as_float((bits >> 9) | 0x3F800000u) - 1.0f;
        uf += TINY; uf = fmaxf(TINY, uf);
        float g = -fast_log(-fast_log(uf));
        float sc = lgpj + g;
        if (j == 0) { bs = sc; bj = tj; blp = lgpj; }
        else if (sc > bs) { bs = sc; bj = tj; blp = lgpj; }
      }
      // argmax tree, lowest-index-on-tie preserved
      {
        float obs  = __shfl_xor(bs, 1);
        int   obj  = __shfl_xor(bj, 1);
        float oblp = __shfl_xor(blp, 1);
        if (obs > bs || (obs == bs && obj < bj)) { bs = obs; bj = obj; blp = oblp; }
      }
      {
        float obs  = __shfl_xor(bs, 2);
        int   obj  = __shfl_xor(bj, 2);
        float oblp = __shfl_xor(blp, 2);
        if (obs > bs || (obs == bs && obj < bj)) { bs = obs; bj = obj; blp = oblp; }
      }
      float ept = ep + __shfl_xor(ep, 1);
      ept += __shfl_xor(ept, 2);
      float ent = -ept;
      const int tok = bj;

      // state update (all 4 quad threads, identically)
      cnt += -1 + (tok < 4 ? 2 : (tok < 8 ? 1 : 0));
      act = act && (cnt > 0);
      lengths += act ? 1 : 0;
      if (tok >= 9) hasvar = true;
      pack |= (uint64_t)(uint32_t)tok << (4 * t);

      if (q == 0) {
        if (gseq < n) {
          o_ent[(size_t)gseq * 12 + t] = ent;
          o_lp [(size_t)gseq * 12 + t] = blp;
          o_msk[(size_t)gseq * 13 + t + 1] = act ? 1.f : 0.f;
        }
        // parent & sibling from packed tokens
        int np0, np1;
        if (tok < 8) { np0 = tok; np1 = -1; }
        else {
          int c = 0, p0 = -1, p1 = -1;
          for (int i = t; i >= 0; --i) {
            int tk = (int)((pack >> (4 * i)) & 15u);
            c += (tk < 4 ? 2 : (tk < 8 ? 1 : 0)) - 1;
            if (c == 0 && p0 < 0) {
              p0 = tk;
              p1 = (i < t) ? (int)((pack >> (4 * (i + 1))) & 15u) : -1;
            }
          }
          np0 = p0; np1 = p1;
        }
        ps0w[wv][wsq] = np0; ps1w[wv][wsq] = np1;
      }
    }
    WAVE_LDS_FENCE();

    if (t < MSTEPS - 1) {
      // ---- epilogue: h_next = tanh((xw + z) + b), write to own wave tile ----
      float hnew[4][8];
      #pragma unroll
      for (int s = 0; s < 4; ++s) {
        const int sq = srow + s;
        const int p0 = ps0w[wv][sq], p1 = ps1w[wv][sq];
        float av[8], cv[8];
        #pragma unroll
        for (int c = 0; c < 8; ++c) { av[c] = 0.f; cv[c] = 0.f; }
        if (p0 >= 0) {
          float4 u0 = *(const float4*)&Wx[p0 * HID + cbase];
          float4 u1 = *(const float4*)&Wx[p0 * HID + cbase + 4];
          av[0]=u0.x; av[1]=u0.y; av[2]=u0.z; av[3]=u0.w;
          av[4]=u1.x; av[5]=u1.y; av[6]=u1.z; av[7]=u1.w;
        }
        if (p1 >= 0) {
          float4 u0 = *(const float4*)&Wx[(NTOK + p1) * HID + cbase];
          float4 u1 = *(const float4*)&Wx[(NTOK + p1) * HID + cbase + 4];
          cv[0]=u0.x; cv[1]=u0.y; cv[2]=u0.z; cv[3]=u0.w;
          cv[4]=u1.x; cv[5]=u1.y; cv[6]=u1.z; cv[7]=u1.w;
        }
        #pragma unroll
        for (int c = 0; c < 8; ++c) {
          float zz = t == 0 ? z1s[cbase + c]
                            : ((c & 1) ? acc2[s][c >> 1].y : acc2[s][c >> 1].x);
          hnew[s][c] = fast_tanh(((av[c] + cv[c]) + zz) + bb[c]);
        }
      }
      #pragma unroll
      for (int c = 0; c < 8; ++c) {
        const int col = cbase + c;
        const int wb  = col * 16 + ((sgl ^ ((col >> 3) & 3)) << 2);
        *(float4*)&hb[wb] =
            make_float4(hnew[0][c], hnew[1][c], hnew[2][c], hnew[3][c]);
      }
    }
    WAVE_LDS_FENCE();
  }

  if (q == 0 && gseq < n) {
    o_cnt[gseq] = (float)cnt;
    o_len[gseq] = (float)lengths;
    #pragma unroll
    for (int j = 0; j < MSTEPS; ++j)
      o_seq[(size_t)gseq * 12 + j] = (float)((pack >> (4 * j)) & 15u);
  }
}

extern "C" void kernel_launch(void* const* d_in, const int* in_sizes, int n_in,
                              void* d_out, int out_size, void* d_ws, size_t ws_size,
                              hipStream_t stream) {
  const float* x0 = (const float*)d_in[1];
  const float* h0 = (const float*)d_in[2];
  const float* Wx = (const float*)d_in[3];
  const float* Wh = (const float*)d_in[4];
  const float* bv = (const float*)d_in[5];
  const float* Wp = (const float*)d_in[6];
  const float* bp = (const float*)d_in[7];
  float* out = (float*)d_out;

  int n = out_size / 51;   // 12+12+12+1+1+13 floats per sequence

  // jax.random.split(jax.random.key(42), 12), partitionable threefry:
  // keys[t] = threefry((0,42), (0, t)).
  KeyArr ka;
  for (int t = 0; t < 12; ++t) {
    uint32_t o0, o1;
    tf2x32(0u, 42u, 0u, (uint32_t)t, o0, o1);
    ka.k0[t] = o0; ka.k1[t] = o1;
  }

  int blocks = (n + SPB - 1) / SPB;
  eq_sampler<<<blocks, TPB, 0, stream>>>(x0, h0, Wx, Wh, bv, Wp, bp, out, n, ka);
}